// Round 1
// baseline (580.877 us; speedup 1.0000x reference)
//
#include <hip/hip_runtime.h>

typedef __attribute__((ext_vector_type(4))) float f32x4;
typedef __attribute__((ext_vector_type(8))) __bf16 bf16x8;
typedef __attribute__((ext_vector_type(8))) short s16x8;

__device__ __forceinline__ short f2bf(float f){
  union { float f; unsigned u; } v; v.f = f;
  unsigned r = v.u + 0x7fffu + ((v.u >> 16) & 1u);
  return (short)(r >> 16);
}
__device__ __forceinline__ float bf2f(short h){
  union { unsigned u; float f; } v; v.u = ((unsigned)(unsigned short)h) << 16; return v.f;
}
__device__ __forceinline__ bf16x8 ldb8(const short* p){ return *(const bf16x8*)p; }

#define LOG2E 1.4426950408889634f

// ---------------- K0: weight prep (fp32 -> bf16, fold 1/16 into q rows) ----
__global__ __launch_bounds__(256) void prep_w(
    const float* __restrict__ qkvw, const float* __restrict__ qkvb,
    const float* __restrict__ pw, const float* __restrict__ pb,
    short* __restrict__ wq, short* __restrict__ bq,
    short* __restrict__ wp, float* __restrict__ bpo){
  const int tid = blockIdx.x*256 + threadIdx.x;
  const int nthr = gridDim.x*256;
  for (int i = tid; i < 768*256; i += nthr){
    float v = qkvw[i];
    if (i < 256*256) v *= 0.0625f;     // q rows scaled by c^-0.5
    wq[i] = f2bf(v);
  }
  for (int i = tid; i < 256*256; i += nthr) wp[i] = f2bf(pw[i]);
  if (tid < 768){ float v = qkvb[tid]; if (tid < 256) v *= 0.0625f; bq[tid] = f2bf(v); }
  if (tid < 256) bpo[tid] = pb[tid];
}

// ---------------- K1: groupnorm stats (mean, rstd per (b,g)) ---------------
__global__ __launch_bounds__(256) void gn_stats(const float* __restrict__ x,
                                                float* __restrict__ stats){
  const int bg = blockIdx.x;                 // 0..255 = b*32+g
  const float* p = x + (size_t)bg * 32768;   // 8 ch * 4096 contiguous
  const int t = threadIdx.x;
  float s1 = 0.f, s2 = 0.f;
  #pragma unroll
  for (int i = 0; i < 32; i++){
    f32x4 v = *(const f32x4*)(p + i*1024 + t*4);
    s1 += v[0]+v[1]+v[2]+v[3];
    s2 += v[0]*v[0]+v[1]*v[1]+v[2]*v[2]+v[3]*v[3];
  }
  #pragma unroll
  for (int off = 1; off < 64; off <<= 1){
    s1 += __shfl_xor(s1, off);
    s2 += __shfl_xor(s2, off);
  }
  __shared__ float a1[4], a2[4];
  const int w = t >> 6;
  if ((t & 63) == 0){ a1[w] = s1; a2[w] = s2; }
  __syncthreads();
  if (t == 0){
    float S1 = a1[0]+a1[1]+a1[2]+a1[3];
    float S2 = a2[0]+a2[1]+a2[2]+a2[3];
    float mu = S1 * (1.f/32768.f);
    float var = S2 * (1.f/32768.f) - mu*mu;
    stats[bg*2]   = mu;
    stats[bg*2+1] = rsqrtf(var + 1e-5f);
  }
}

// ---------------- K2: normalize + transpose -> h_t[b][n][c] bf16 -----------
__global__ __launch_bounds__(256) void gn_apply(
    const float* __restrict__ x, const float* __restrict__ stats,
    const float* __restrict__ nw, const float* __restrict__ nb,
    short* __restrict__ h_t){
  const int bx = blockIdx.x;
  const int b = bx >> 8; const int rem = bx & 255;
  const int ctile = rem >> 6, ntile = rem & 63;
  const int c0 = ctile << 6, n0 = ntile << 6;
  const int t = threadIdx.x;
  __shared__ short lt[64][72];
  {
    const int cl = t >> 2, nch = (t & 3) << 4;
    const int c = c0 + cl;
    const float mu   = stats[((b<<5) + (c>>3))*2];
    const float rstd = stats[((b<<5) + (c>>3))*2 + 1];
    const float A = rstd * nw[c];
    const float Bc = nb[c] - mu * A;
    const float* px = x + (((size_t)(b<<8) + c) << 12) + n0 + nch;
    #pragma unroll
    for (int j = 0; j < 4; j++){
      f32x4 v = *(const f32x4*)(px + j*4);
      lt[nch + j*4 + 0][cl] = f2bf(v[0]*A + Bc);
      lt[nch + j*4 + 1][cl] = f2bf(v[1]*A + Bc);
      lt[nch + j*4 + 2][cl] = f2bf(v[2]*A + Bc);
      lt[nch + j*4 + 3][cl] = f2bf(v[3]*A + Bc);
    }
  }
  __syncthreads();
  {
    const int nl = t >> 2, cch = (t & 3) << 4;
    s16x8 a0 = *(const s16x8*)&lt[nl][cch];
    s16x8 a1 = *(const s16x8*)&lt[nl][cch + 8];
    short* dst = h_t + (((size_t)(b<<12) + n0 + nl) << 8) + c0 + cch;
    *(s16x8*)dst = a0;
    *(s16x8*)(dst + 8) = a1;
  }
}

// ---------------- K3: qkv GEMM (bf16 MFMA, frags direct from global) -------
__global__ __launch_bounds__(256) void qkv_gemm(
    const short* __restrict__ h_t, const short* __restrict__ wq,
    const short* __restrict__ bq, short* __restrict__ q_t,
    short* __restrict__ k_t, short* __restrict__ v_buf){
  const int bx = blockIdx.x;
  const int b = bx / 768; const int rem = bx - b*768;
  const int nt = rem / 12, ot = rem - nt*12;
  const int n0 = nt << 6, co0 = ot << 6;
  const int t = threadIdx.x, w = t >> 6, lane = t & 63;
  const int lr = lane & 15, lg = lane >> 4;
  f32x4 acc[4] = { {0,0,0,0},{0,0,0,0},{0,0,0,0},{0,0,0,0} };
  if (co0 < 512){
    // q/k: M = n rows, N = out-channel cols
    const short* pa = h_t + (((size_t)b*4096 + n0 + w*16 + lr) << 8) + lg*8;
    #pragma unroll
    for (int kk = 0; kk < 8; kk++){
      bf16x8 a = ldb8(pa + kk*32);
      #pragma unroll
      for (int tt = 0; tt < 4; tt++){
        bf16x8 bb = ldb8(wq + (((size_t)(co0 + tt*16 + lr)) << 8) + kk*32 + lg*8);
        acc[tt] = __builtin_amdgcn_mfma_f32_16x16x32_bf16(a, bb, acc[tt], 0, 0, 0);
      }
    }
    #pragma unroll
    for (int tt = 0; tt < 4; tt++){
      const int col = co0 + tt*16 + lr;
      const float bias = bf2f(bq[col]);
      short* dst; int cc;
      if (col < 256){ dst = q_t; cc = col; } else { dst = k_t; cc = col - 256; }
      #pragma unroll
      for (int i = 0; i < 4; i++){
        const int row = n0 + w*16 + lg*4 + i;
        dst[(((size_t)b*4096 + row) << 8) + cc] = f2bf(acc[tt][i] + bias);
      }
    }
  } else {
    // v: swap roles -> M = out-channel rows, N = n cols -> natural [c][n] writes
    const short* pa = wq + (((size_t)(co0 + w*16 + lr)) << 8) + lg*8;
    #pragma unroll
    for (int kk = 0; kk < 8; kk++){
      bf16x8 a = ldb8(pa + kk*32);
      #pragma unroll
      for (int tt = 0; tt < 4; tt++){
        bf16x8 bb = ldb8(h_t + (((size_t)b*4096 + n0 + tt*16 + lr) << 8) + kk*32 + lg*8);
        acc[tt] = __builtin_amdgcn_mfma_f32_16x16x32_bf16(a, bb, acc[tt], 0, 0, 0);
      }
    }
    #pragma unroll
    for (int i = 0; i < 4; i++){
      const int co = co0 + w*16 + lg*4 + i;
      const float bias = bf2f(bq[co]);
      #pragma unroll
      for (int tt = 0; tt < 4; tt++){
        const int col = n0 + tt*16 + lr;
        v_buf[(((size_t)(b*256 + co - 512)) << 12) + col] = f2bf(acc[tt][i] + bias);
      }
    }
  }
}

// ---------------- K4: flash attention (QB=128, KB=32, 8 waves) -------------
__global__ __launch_bounds__(512, 2) void attn_flash(
    const short* __restrict__ q_t, const short* __restrict__ k_t,
    const short* __restrict__ v_b, short* __restrict__ o_t){
  const int bx = blockIdx.x;
  const int b = bx >> 5, qt = bx & 31;
  const int q0 = qt * 128;
  const int t = threadIdx.x, w = t >> 6, lane = t & 63;
  const int lr = lane & 15, lg = lane >> 4;

  __shared__ short Kl[32][264];   // [key][d], pad to break 512B-stride conflicts
  __shared__ short Vl[256][40];   // [c][key], pad 32->40
  __shared__ short Pl[128][40];   // [q][key]

  // Q fragments in registers (row = q, k-dim = d contiguous)
  bf16x8 qf[8];
  {
    const short* pq = q_t + (((size_t)b*4096 + q0 + w*16 + lr) << 8) + lg*8;
    #pragma unroll
    for (int kk = 0; kk < 8; kk++) qf[kk] = ldb8(pq + kk*32);
  }
  f32x4 of[16];
  #pragma unroll
  for (int i = 0; i < 16; i++) of[i] = (f32x4){0.f,0.f,0.f,0.f};
  float mx[4] = {-1e30f,-1e30f,-1e30f,-1e30f};
  float ls[4] = {0.f,0.f,0.f,0.f};

  const short* kbase = k_t + (((size_t)b*4096) << 8);
  const short* vbase = v_b + (((size_t)b*256) << 12);

  const int kr = t >> 5, kc = (t & 31) << 3;   // K tile: rows kr, kr+16
  const int vc = t >> 2, vk = (t & 3) << 3;    // V tile: rows vc, vc+128

  s16x8 rk0, rk1, rv0, rv1;
  {
    rk0 = *(const s16x8*)(kbase + (size_t)kr*256 + kc);
    rk1 = *(const s16x8*)(kbase + (size_t)(kr+16)*256 + kc);
    rv0 = *(const s16x8*)(vbase + (size_t)vc*4096 + vk);
    rv1 = *(const s16x8*)(vbase + (size_t)(vc+128)*4096 + vk);
  }

  for (int kt2 = 0; kt2 < 128; kt2++){
    *(s16x8*)&Kl[kr][kc]      = rk0;
    *(s16x8*)&Kl[kr+16][kc]   = rk1;
    *(s16x8*)&Vl[vc][vk]      = rv0;
    *(s16x8*)&Vl[vc+128][vk]  = rv1;
    __syncthreads();

    // prefetch next tile (wraps on last iter; harmless) - hides HBM/L3 latency
    {
      const int k0n = ((kt2 + 1) & 127) * 32;
      const short* kp = kbase + (size_t)k0n*256 + kc;
      rk0 = *(const s16x8*)(kp + (size_t)kr*256);
      rk1 = *(const s16x8*)(kp + (size_t)(kr+16)*256);
      const short* vp = vbase + k0n + vk;
      rv0 = *(const s16x8*)(vp + (size_t)vc*4096);
      rv1 = *(const s16x8*)(vp + (size_t)(vc+128)*4096);
    }

    // S = Q K'^T  (16q x 32k per wave)
    f32x4 sf0 = {0,0,0,0}, sf1 = {0,0,0,0};
    #pragma unroll
    for (int kk = 0; kk < 8; kk++){
      bf16x8 bb0 = ldb8(&Kl[lr][kk*32 + lg*8]);
      bf16x8 bb1 = ldb8(&Kl[16 + lr][kk*32 + lg*8]);
      sf0 = __builtin_amdgcn_mfma_f32_16x16x32_bf16(qf[kk], bb0, sf0, 0, 0, 0);
      sf1 = __builtin_amdgcn_mfma_f32_16x16x32_bf16(qf[kk], bb1, sf1, 0, 0, 0);
    }

    // online softmax (rows r = lg*4+i; 16 lanes per row-group share low 4 bits)
    float tm[4], mn[4], corr[4], rsum[4];
    #pragma unroll
    for (int i = 0; i < 4; i++) tm[i] = fmaxf(sf0[i], sf1[i]);
    #pragma unroll
    for (int off = 1; off < 16; off <<= 1){
      #pragma unroll
      for (int i = 0; i < 4; i++) tm[i] = fmaxf(tm[i], __shfl_xor(tm[i], off));
    }
    #pragma unroll
    for (int i = 0; i < 4; i++){
      mn[i] = fmaxf(mx[i], tm[i]);
      corr[i] = exp2f((mx[i] - mn[i]) * LOG2E);
      mx[i] = mn[i];
    }
    #pragma unroll
    for (int i = 0; i < 4; i++){
      float p0 = exp2f((sf0[i] - mn[i]) * LOG2E);
      float p1 = exp2f((sf1[i] - mn[i]) * LOG2E);
      rsum[i] = p0 + p1;
      Pl[w*16 + lg*4 + i][lr]      = f2bf(p0);
      Pl[w*16 + lg*4 + i][16 + lr] = f2bf(p1);
    }
    #pragma unroll
    for (int off = 1; off < 16; off <<= 1){
      #pragma unroll
      for (int i = 0; i < 4; i++) rsum[i] += __shfl_xor(rsum[i], off);
    }
    #pragma unroll
    for (int i = 0; i < 4; i++) ls[i] = ls[i]*corr[i] + rsum[i];
    #pragma unroll
    for (int f = 0; f < 16; f++){
      of[f][0] *= corr[0]; of[f][1] *= corr[1];
      of[f][2] *= corr[2]; of[f][3] *= corr[3];
    }

    // PV: O[q][c] += P[q][k] * V[c][k]  (P rows are wave-private -> no barrier)
    bf16x8 pa = ldb8(&Pl[w*16 + lr][lg*8]);
    #pragma unroll
    for (int ct = 0; ct < 16; ct++){
      bf16x8 vb2 = ldb8(&Vl[ct*16 + lr][lg*8]);
      of[ct] = __builtin_amdgcn_mfma_f32_16x16x32_bf16(pa, vb2, of[ct], 0, 0, 0);
    }
    __syncthreads();
  }

  // epilogue: O / l -> o_t[b][q][c] bf16
  short* po = o_t + (((size_t)b*4096 + q0 + w*16) << 8);
  #pragma unroll
  for (int i = 0; i < 4; i++){
    const float inv = 1.0f / ls[i];
    const int row = lg*4 + i;
    #pragma unroll
    for (int ct = 0; ct < 16; ct++){
      po[(size_t)row*256 + ct*16 + lr] = f2bf(of[ct][i] * inv);
    }
  }
}

// ---------------- K5: proj GEMM + bias + residual --------------------------
__global__ __launch_bounds__(256) void proj_gemm(
    const short* __restrict__ o_t, const short* __restrict__ wp,
    const float* __restrict__ bp, const float* __restrict__ x,
    float* __restrict__ out){
  const int bx = blockIdx.x;
  const int b = bx >> 8; const int rem = bx & 255;
  const int ct = rem >> 6, qt = rem & 63;
  const int co0 = ct << 6, q0 = qt << 6;
  const int t = threadIdx.x, w = t >> 6, lane = t & 63;
  const int lr = lane & 15, lg = lane >> 4;
  f32x4 acc[4] = { {0,0,0,0},{0,0,0,0},{0,0,0,0},{0,0,0,0} };
  const short* pa = wp + (((size_t)(co0 + w*16 + lr)) << 8) + lg*8;
  #pragma unroll
  for (int kk = 0; kk < 8; kk++){
    bf16x8 a = ldb8(pa + kk*32);
    #pragma unroll
    for (int tt = 0; tt < 4; tt++){
      bf16x8 bb = ldb8(o_t + (((size_t)b*4096 + q0 + tt*16 + lr) << 8) + kk*32 + lg*8);
      acc[tt] = __builtin_amdgcn_mfma_f32_16x16x32_bf16(a, bb, acc[tt], 0, 0, 0);
    }
  }
  #pragma unroll
  for (int i = 0; i < 4; i++){
    const int co = co0 + w*16 + lg*4 + i;
    const float bias = bp[co];
    #pragma unroll
    for (int tt = 0; tt < 4; tt++){
      const int q = q0 + tt*16 + lr;
      const size_t idx = (((size_t)(b*256 + co)) << 12) + q;
      out[idx] = acc[tt][i] + bias + x[idx];
    }
  }
}

// ---------------- workspace layout -----------------------------------------
static constexpr size_t SZT  = (size_t)8 * 4096 * 256 * 2;  // 16 MB bf16 tensor
static constexpr size_t OFF_STATS = 0;                      // 2 KB
static constexpr size_t OFF_WQ = 4096;                      // 768*256*2
static constexpr size_t OFF_BQ = OFF_WQ + 768*256*2;
static constexpr size_t OFF_WP = OFF_BQ + 768*2;
static constexpr size_t OFF_BP = OFF_WP + 256*256*2;
static constexpr size_t OFF_HT = 532480;
static constexpr size_t OFF_QT = OFF_HT + SZT;
static constexpr size_t OFF_KT = OFF_QT + SZT;
static constexpr size_t OFF_V  = OFF_KT + SZT;
static constexpr size_t OFF_OT = OFF_V + SZT;

extern "C" void kernel_launch(void* const* d_in, const int* in_sizes, int n_in,
                              void* d_out, int out_size, void* d_ws, size_t ws_size,
                              hipStream_t stream){
  const float* x    = (const float*)d_in[0];
  const float* nw   = (const float*)d_in[1];
  const float* nb   = (const float*)d_in[2];
  const float* qkvw = (const float*)d_in[3];
  const float* qkvb = (const float*)d_in[4];
  const float* pw   = (const float*)d_in[5];
  const float* pb   = (const float*)d_in[6];
  float* out = (float*)d_out;
  char* ws = (char*)d_ws;

  float* stats = (float*)(ws + OFF_STATS);
  short* wq    = (short*)(ws + OFF_WQ);
  short* bq    = (short*)(ws + OFF_BQ);
  short* wp    = (short*)(ws + OFF_WP);
  float* bp    = (float*)(ws + OFF_BP);
  short* ht    = (short*)(ws + OFF_HT);
  short* qt    = (short*)(ws + OFF_QT);
  short* kt    = (short*)(ws + OFF_KT);
  short* vb    = (short*)(ws + OFF_V);
  short* ot    = (short*)(ws + OFF_OT);

  prep_w   <<<256,  256, 0, stream>>>(qkvw, qkvb, pw, pb, wq, bq, wp, bp);
  gn_stats <<<256,  256, 0, stream>>>(x, stats);
  gn_apply <<<2048, 256, 0, stream>>>(x, stats, nw, nb, ht);
  qkv_gemm <<<6144, 256, 0, stream>>>(ht, wq, bq, qt, kt, vb);
  attn_flash<<<256, 512, 0, stream>>>(qt, kt, vb, ot);
  proj_gemm<<<2048, 256, 0, stream>>>(ot, wp, bp, x, out);
}

// Round 2
// 472.497 us; speedup vs baseline: 1.2294x; 1.2294x over previous
//
#include <hip/hip_runtime.h>

typedef __attribute__((ext_vector_type(4))) float f32x4;
typedef __attribute__((ext_vector_type(16))) float f32x16;
typedef __attribute__((ext_vector_type(8))) __bf16 bf16x8;
typedef __attribute__((ext_vector_type(8))) short s16x8;

__device__ __forceinline__ short f2bf(float f){
  union { float f; unsigned u; } v; v.f = f;
  unsigned r = v.u + 0x7fffu + ((v.u >> 16) & 1u);
  return (short)(r >> 16);
}
__device__ __forceinline__ float bf2f(short h){
  union { unsigned u; float f; } v; v.u = ((unsigned)(unsigned short)h) << 16; return v.f;
}
__device__ __forceinline__ bf16x8 ldb8(const short* p){ return *(const bf16x8*)p; }
__device__ __forceinline__ unsigned pk2(float a, float b){
  return (unsigned)(unsigned short)f2bf(a) | ((unsigned)(unsigned short)f2bf(b) << 16);
}

#define LOG2E 1.4426950408889634f

// ---------------- K0: weight prep (fp32 -> bf16, fold 1/16 into q rows) ----
__global__ __launch_bounds__(256) void prep_w(
    const float* __restrict__ qkvw, const float* __restrict__ qkvb,
    const float* __restrict__ pw, const float* __restrict__ pb,
    short* __restrict__ wq, short* __restrict__ bq,
    short* __restrict__ wp, float* __restrict__ bpo){
  const int tid = blockIdx.x*256 + threadIdx.x;
  const int nthr = gridDim.x*256;
  for (int i = tid; i < 768*256; i += nthr){
    float v = qkvw[i];
    if (i < 256*256) v *= 0.0625f;     // q rows scaled by c^-0.5
    wq[i] = f2bf(v);
  }
  for (int i = tid; i < 256*256; i += nthr) wp[i] = f2bf(pw[i]);
  if (tid < 768){ float v = qkvb[tid]; if (tid < 256) v *= 0.0625f; bq[tid] = f2bf(v); }
  if (tid < 256) bpo[tid] = pb[tid];
}

// ---------------- K1: groupnorm stats (mean, rstd per (b,g)) ---------------
__global__ __launch_bounds__(256) void gn_stats(const float* __restrict__ x,
                                                float* __restrict__ stats){
  const int bg = blockIdx.x;                 // 0..255 = b*32+g
  const float* p = x + (size_t)bg * 32768;   // 8 ch * 4096 contiguous
  const int t = threadIdx.x;
  float s1 = 0.f, s2 = 0.f;
  #pragma unroll
  for (int i = 0; i < 32; i++){
    f32x4 v = *(const f32x4*)(p + i*1024 + t*4);
    s1 += v[0]+v[1]+v[2]+v[3];
    s2 += v[0]*v[0]+v[1]*v[1]+v[2]*v[2]+v[3]*v[3];
  }
  #pragma unroll
  for (int off = 1; off < 64; off <<= 1){
    s1 += __shfl_xor(s1, off);
    s2 += __shfl_xor(s2, off);
  }
  __shared__ float a1[4], a2[4];
  const int w = t >> 6;
  if ((t & 63) == 0){ a1[w] = s1; a2[w] = s2; }
  __syncthreads();
  if (t == 0){
    float S1 = a1[0]+a1[1]+a1[2]+a1[3];
    float S2 = a2[0]+a2[1]+a2[2]+a2[3];
    float mu = S1 * (1.f/32768.f);
    float var = S2 * (1.f/32768.f) - mu*mu;
    stats[bg*2]   = mu;
    stats[bg*2+1] = rsqrtf(var + 1e-5f);
  }
}

// ---------------- K2: normalize + transpose -> h_t[b][n][c] bf16 -----------
__global__ __launch_bounds__(256) void gn_apply(
    const float* __restrict__ x, const float* __restrict__ stats,
    const float* __restrict__ nw, const float* __restrict__ nb,
    short* __restrict__ h_t){
  const int bx = blockIdx.x;
  const int b = bx >> 8; const int rem = bx & 255;
  const int ctile = rem >> 6, ntile = rem & 63;
  const int c0 = ctile << 6, n0 = ntile << 6;
  const int t = threadIdx.x;
  __shared__ short lt[64][72];
  {
    const int cl = t >> 2, nch = (t & 3) << 4;
    const int c = c0 + cl;
    const float mu   = stats[((b<<5) + (c>>3))*2];
    const float rstd = stats[((b<<5) + (c>>3))*2 + 1];
    const float A = rstd * nw[c];
    const float Bc = nb[c] - mu * A;
    const float* px = x + (((size_t)(b<<8) + c) << 12) + n0 + nch;
    #pragma unroll
    for (int j = 0; j < 4; j++){
      f32x4 v = *(const f32x4*)(px + j*4);
      lt[nch + j*4 + 0][cl] = f2bf(v[0]*A + Bc);
      lt[nch + j*4 + 1][cl] = f2bf(v[1]*A + Bc);
      lt[nch + j*4 + 2][cl] = f2bf(v[2]*A + Bc);
      lt[nch + j*4 + 3][cl] = f2bf(v[3]*A + Bc);
    }
  }
  __syncthreads();
  {
    const int nl = t >> 2, cch = (t & 3) << 4;
    s16x8 a0 = *(const s16x8*)&lt[nl][cch];
    s16x8 a1 = *(const s16x8*)&lt[nl][cch + 8];
    short* dst = h_t + (((size_t)(b<<12) + n0 + nl) << 8) + c0 + cch;
    *(s16x8*)dst = a0;
    *(s16x8*)(dst + 8) = a1;
  }
}

// ---------------- K3: qkv GEMM (bf16 MFMA, frags direct from global) -------
__global__ __launch_bounds__(256) void qkv_gemm(
    const short* __restrict__ h_t, const short* __restrict__ wq,
    const short* __restrict__ bq, short* __restrict__ q_t,
    short* __restrict__ k_t, short* __restrict__ v_buf){
  const int bx = blockIdx.x;
  const int b = bx / 768; const int rem = bx - b*768;
  const int nt = rem / 12, ot = rem - nt*12;
  const int n0 = nt << 6, co0 = ot << 6;
  const int t = threadIdx.x, w = t >> 6, lane = t & 63;
  const int lr = lane & 15, lg = lane >> 4;
  f32x4 acc[4] = { {0,0,0,0},{0,0,0,0},{0,0,0,0},{0,0,0,0} };
  if (co0 < 512){
    // q/k: M = n rows, N = out-channel cols
    const short* pa = h_t + (((size_t)b*4096 + n0 + w*16 + lr) << 8) + lg*8;
    #pragma unroll
    for (int kk = 0; kk < 8; kk++){
      bf16x8 a = ldb8(pa + kk*32);
      #pragma unroll
      for (int tt = 0; tt < 4; tt++){
        bf16x8 bb = ldb8(wq + (((size_t)(co0 + tt*16 + lr)) << 8) + kk*32 + lg*8);
        acc[tt] = __builtin_amdgcn_mfma_f32_16x16x32_bf16(a, bb, acc[tt], 0, 0, 0);
      }
    }
    #pragma unroll
    for (int tt = 0; tt < 4; tt++){
      const int col = co0 + tt*16 + lr;
      const float bias = bf2f(bq[col]);
      short* dst; int cc;
      if (col < 256){ dst = q_t; cc = col; } else { dst = k_t; cc = col - 256; }
      #pragma unroll
      for (int i = 0; i < 4; i++){
        const int row = n0 + w*16 + lg*4 + i;
        dst[(((size_t)b*4096 + row) << 8) + cc] = f2bf(acc[tt][i] + bias);
      }
    }
  } else {
    // v: swap roles -> M = out-channel rows, N = n cols -> natural [c][n] writes
    const short* pa = wq + (((size_t)(co0 + w*16 + lr)) << 8) + lg*8;
    #pragma unroll
    for (int kk = 0; kk < 8; kk++){
      bf16x8 a = ldb8(pa + kk*32);
      #pragma unroll
      for (int tt = 0; tt < 4; tt++){
        bf16x8 bb = ldb8(h_t + (((size_t)b*4096 + n0 + tt*16 + lr) << 8) + kk*32 + lg*8);
        acc[tt] = __builtin_amdgcn_mfma_f32_16x16x32_bf16(a, bb, acc[tt], 0, 0, 0);
      }
    }
    #pragma unroll
    for (int i = 0; i < 4; i++){
      const int co = co0 + w*16 + lg*4 + i;
      const float bias = bf2f(bq[co]);
      #pragma unroll
      for (int tt = 0; tt < 4; tt++){
        const int col = n0 + tt*16 + lr;
        v_buf[(((size_t)(b*256 + co - 512)) << 12) + col] = f2bf(acc[tt][i] + bias);
      }
    }
  }
}

// ---------------- K4: flash attention v2 -----------------------------------
// 4 waves x 32 q-rows (QB=128), KB=32, 32x32x16 MFMA, swapped QK^T softmax,
// global_load_lds double-buffered staging with XOR-swizzled K/V LDS tiles.
__global__ __launch_bounds__(256, 2) void attn_flash(
    const short* __restrict__ q_t, const short* __restrict__ k_t,
    const short* __restrict__ v_b, short* __restrict__ o_t){
  const int b  = blockIdx.x & 7;          // batch -> XCD co-location
  const int qt = blockIdx.x >> 3;
  const int t = threadIdx.x, w = t >> 6, l = t & 63;
  const int lq = l & 31, hi = l >> 5;
  const int q0 = qt*128 + w*32;

  // [buf:2][ K: 32 keys x 512B (swz ^(key&7)<<4) | V: 256 c x 64B (swz ^((c>>1)&3)<<4) ]
  __shared__ short smem[32768];   // 64 KB
  char* lds = (char*)smem;

  // ---- Q fragments in registers (B-operand: col=q=lq, k=d) ----
  bf16x8 qf[16];
  {
    const short* pq = q_t + (((size_t)b*4096 + q0 + lq) << 8) + hi*8;
    #pragma unroll
    for (int ks = 0; ks < 16; ks++) qf[ks] = ldb8(pq + ks*16);
  }
  f32x16 of[8];
  #pragma unroll
  for (int ct = 0; ct < 8; ct++)
    #pragma unroll
    for (int r = 0; r < 16; r++) of[ct][r] = 0.f;
  float m_run = -1.0e30f, l_run = 0.f;

  // ---- staging source addresses (pre-swizzled global, linear LDS dest) ----
  const char* kbase = (const char*)(k_t + (((size_t)b*4096) << 8));
  const char* vbase = (const char*)(v_b + (((size_t)b*256) << 12));
  const char* ksrc[4]; const char* vsrc[4];
  #pragma unroll
  for (int j = 0; j < 4; j++){
    const int key = w*8 + j*2 + hi;
    ksrc[j] = kbase + key*512 + (((l&31)*16) ^ ((key&7)<<4));
    const int c = w*64 + j*16 + (l>>2);
    vsrc[j] = vbase + (size_t)c*8192 + (((l&3)*16) ^ (((c>>1)&3)<<4));
  }

  #define STAGE(buf, kt_) do {                                               \
    _Pragma("unroll")                                                        \
    for (int j = 0; j < 4; j++)                                              \
      __builtin_amdgcn_global_load_lds(                                      \
        (const __attribute__((address_space(1))) unsigned*)(ksrc[j] + (size_t)(kt_)*16384), \
        (__attribute__((address_space(3))) unsigned*)(lds + (buf)*32768 + w*4096 + j*1024), \
        16, 0, 0);                                                           \
    _Pragma("unroll")                                                        \
    for (int j = 0; j < 4; j++)                                              \
      __builtin_amdgcn_global_load_lds(                                      \
        (const __attribute__((address_space(1))) unsigned*)(vsrc[j] + (size_t)(kt_)*64),    \
        (__attribute__((address_space(3))) unsigned*)(lds + (buf)*32768 + 16384 + w*4096 + j*1024), \
        16, 0, 0);                                                           \
  } while (0)

  STAGE(0, 0);
  __syncthreads();

  const int hi16 = hi*16;
  const int swzKr = (lq & 7) << 4;
  const int swzV  = ((lq >> 1) & 3) << 4;
  int cur = 0;

  for (int kt = 0; kt < 128; kt++){
    if (kt < 127) STAGE(cur^1, kt+1);
    const char* Kb = lds + cur*32768;
    const char* Vb = lds + cur*32768 + 16384;

    // ---- S^T = mfma(K, Q): D[key][q], lane: col q=lq, rows=keys ----
    f32x16 sf;
    #pragma unroll
    for (int r = 0; r < 16; r++) sf[r] = 0.f;
    #pragma unroll
    for (int ks = 0; ks < 16; ks++){
      bf16x8 kf = ldb8((const short*)(Kb + (lq<<9) + ((ks*32 + hi16) ^ swzKr)));
      sf = __builtin_amdgcn_mfma_f32_32x32x16_bf16(kf, qf[ks], sf, 0, 0, 0);
    }

    // ---- online softmax, fully in-register (lane pair l <-> l^32) ----
    float pm = sf[0];
    #pragma unroll
    for (int r = 1; r < 16; r++) pm = fmaxf(pm, sf[r]);
    pm = fmaxf(pm, __shfl_xor(pm, 32));
    if (!__all(pm <= m_run + 8.f)){          // defer-max (THR=8)
      const float mn = fmaxf(m_run, pm);
      const float corr = exp2f((m_run - mn) * LOG2E);
      #pragma unroll
      for (int ct = 0; ct < 8; ct++)
        #pragma unroll
        for (int r = 0; r < 16; r++) of[ct][r] *= corr;
      l_run *= corr;
      m_run = mn;
    }
    const float mL = m_run * LOG2E;
    float p[16]; float s = 0.f;
    #pragma unroll
    for (int r = 0; r < 16; r++){
      p[r] = exp2f(__builtin_fmaf(sf[r], LOG2E, -mL));
      s += p[r];
    }
    l_run += s + __shfl_xor(s, 32);

    // ---- pack P -> bf16 A-fragments (exchange halves with lane^32) ----
    unsigned own[8];
    #pragma unroll
    for (int ks = 0; ks < 2; ks++){
      own[ks*4+0] = pk2(p[ks*8+0], p[ks*8+1]);
      own[ks*4+1] = pk2(p[ks*8+2], p[ks*8+3]);
      own[ks*4+2] = pk2(p[ks*8+4], p[ks*8+5]);
      own[ks*4+3] = pk2(p[ks*8+6], p[ks*8+7]);
    }
    unsigned prt[8];
    #pragma unroll
    for (int i = 0; i < 8; i++) prt[i] = __shfl_xor(own[i], 32);
    bf16x8 pfrag[2];
    #pragma unroll
    for (int ks = 0; ks < 2; ks++){
      union { unsigned u[4]; bf16x8 v; } uu;
      uu.u[0] = hi ? prt[ks*4+2] : own[ks*4+0];
      uu.u[1] = hi ? prt[ks*4+3] : own[ks*4+1];
      uu.u[2] = hi ? own[ks*4+2] : prt[ks*4+0];
      uu.u[3] = hi ? own[ks*4+3] : prt[ks*4+1];
      pfrag[ks] = uu.v;
    }

    // ---- PV: O[q][c] += P[q][k] * V[k][c]  (A=P regs, B=V from LDS) ----
    #pragma unroll
    for (int ks = 0; ks < 2; ks++){
      #pragma unroll
      for (int ct = 0; ct < 8; ct++){
        bf16x8 vf = ldb8((const short*)(Vb + ((ct*32 + lq)<<6) + ((ks*32 + hi16) ^ swzV)));
        of[ct] = __builtin_amdgcn_mfma_f32_32x32x16_bf16(pfrag[ks], vf, of[ct], 0, 0, 0);
      }
    }
    __syncthreads();
    cur ^= 1;
  }

  // ---- epilogue: O/l -> o_t[b][q][c] (rows=q in regs, col=c=lane) ----
  short* po = o_t + (((size_t)b*4096 + q0) << 8);
  #pragma unroll
  for (int r = 0; r < 16; r++){
    const int row = (r&3) + 8*(r>>2) + 4*hi;
    const float lv = __shfl(l_run, row);
    const float inv = __builtin_amdgcn_rcpf(lv);
    #pragma unroll
    for (int ct = 0; ct < 8; ct++){
      po[(size_t)row*256 + ct*32 + lq] = f2bf(of[ct][r] * inv);
    }
  }
  #undef STAGE
}

// ---------------- K5: proj GEMM + bias + residual --------------------------
__global__ __launch_bounds__(256) void proj_gemm(
    const short* __restrict__ o_t, const short* __restrict__ wp,
    const float* __restrict__ bp, const float* __restrict__ x,
    float* __restrict__ out){
  const int bx = blockIdx.x;
  const int b = bx >> 8; const int rem = bx & 255;
  const int ct = rem >> 6, qt = rem & 63;
  const int co0 = ct << 6, q0 = qt << 6;
  const int t = threadIdx.x, w = t >> 6, lane = t & 63;
  const int lr = lane & 15, lg = lane >> 4;
  f32x4 acc[4] = { {0,0,0,0},{0,0,0,0},{0,0,0,0},{0,0,0,0} };
  const short* pa = wp + (((size_t)(co0 + w*16 + lr)) << 8) + lg*8;
  #pragma unroll
  for (int kk = 0; kk < 8; kk++){
    bf16x8 a = ldb8(pa + kk*32);
    #pragma unroll
    for (int tt = 0; tt < 4; tt++){
      bf16x8 bb = ldb8(o_t + (((size_t)b*4096 + q0 + tt*16 + lr) << 8) + kk*32 + lg*8);
      acc[tt] = __builtin_amdgcn_mfma_f32_16x16x32_bf16(a, bb, acc[tt], 0, 0, 0);
    }
  }
  #pragma unroll
  for (int i = 0; i < 4; i++){
    const int co = co0 + w*16 + lg*4 + i;
    const float bias = bp[co];
    #pragma unroll
    for (int tt = 0; tt < 4; tt++){
      const int q = q0 + tt*16 + lr;
      const size_t idx = (((size_t)(b*256 + co)) << 12) + q;
      out[idx] = acc[tt][i] + bias + x[idx];
    }
  }
}

// ---------------- workspace layout -----------------------------------------
static constexpr size_t SZT  = (size_t)8 * 4096 * 256 * 2;  // 16 MB bf16 tensor
static constexpr size_t OFF_STATS = 0;                      // 2 KB
static constexpr size_t OFF_WQ = 4096;                      // 768*256*2
static constexpr size_t OFF_BQ = OFF_WQ + 768*256*2;
static constexpr size_t OFF_WP = OFF_BQ + 768*2;
static constexpr size_t OFF_BP = OFF_WP + 256*256*2;
static constexpr size_t OFF_HT = 532480;
static constexpr size_t OFF_QT = OFF_HT + SZT;
static constexpr size_t OFF_KT = OFF_QT + SZT;
static constexpr size_t OFF_V  = OFF_KT + SZT;
static constexpr size_t OFF_OT = OFF_V + SZT;

extern "C" void kernel_launch(void* const* d_in, const int* in_sizes, int n_in,
                              void* d_out, int out_size, void* d_ws, size_t ws_size,
                              hipStream_t stream){
  const float* x    = (const float*)d_in[0];
  const float* nw   = (const float*)d_in[1];
  const float* nb   = (const float*)d_in[2];
  const float* qkvw = (const float*)d_in[3];
  const float* qkvb = (const float*)d_in[4];
  const float* pw   = (const float*)d_in[5];
  const float* pb   = (const float*)d_in[6];
  float* out = (float*)d_out;
  char* ws = (char*)d_ws;

  float* stats = (float*)(ws + OFF_STATS);
  short* wq    = (short*)(ws + OFF_WQ);
  short* bq    = (short*)(ws + OFF_BQ);
  short* wp    = (short*)(ws + OFF_WP);
  float* bp    = (float*)(ws + OFF_BP);
  short* ht    = (short*)(ws + OFF_HT);
  short* qt    = (short*)(ws + OFF_QT);
  short* kt    = (short*)(ws + OFF_KT);
  short* vb    = (short*)(ws + OFF_V);
  short* ot    = (short*)(ws + OFF_OT);

  prep_w   <<<256,  256, 0, stream>>>(qkvw, qkvb, pw, pb, wq, bq, wp, bp);
  gn_stats <<<256,  256, 0, stream>>>(x, stats);
  gn_apply <<<2048, 256, 0, stream>>>(x, stats, nw, nb, ht);
  qkv_gemm <<<6144, 256, 0, stream>>>(ht, wq, bq, qt, kt, vb);
  attn_flash<<<256, 256, 0, stream>>>(qt, kt, vb, ot);
  proj_gemm<<<2048, 256, 0, stream>>>(ot, wp, bp, x, out);
}

// Round 4
// 414.690 us; speedup vs baseline: 1.4008x; 1.1394x over previous
//
#include <hip/hip_runtime.h>

typedef __attribute__((ext_vector_type(4))) float f32x4;
typedef __attribute__((ext_vector_type(16))) float f32x16;
typedef __attribute__((ext_vector_type(8))) __bf16 bf16x8;
typedef __attribute__((ext_vector_type(8))) short s16x8;

__device__ __forceinline__ short f2bf(float f){
  union { float f; unsigned u; } v; v.f = f;
  unsigned r = v.u + 0x7fffu + ((v.u >> 16) & 1u);
  return (short)(r >> 16);
}
__device__ __forceinline__ float bf2f(short h){
  union { unsigned u; float f; } v; v.u = ((unsigned)(unsigned short)h) << 16; return v.f;
}
__device__ __forceinline__ bf16x8 ldb8(const short* p){ return *(const bf16x8*)p; }
__device__ __forceinline__ unsigned pk2(float a, float b){
  return (unsigned)(unsigned short)f2bf(a) | ((unsigned)(unsigned short)f2bf(b) << 16);
}

#define LOG2E 1.4426950408889634f

// ---------------- K0: weight prep (fp32 -> bf16, fold 1/16 into q rows) ----
__global__ __launch_bounds__(256) void prep_w(
    const float* __restrict__ qkvw, const float* __restrict__ qkvb,
    const float* __restrict__ pw, const float* __restrict__ pb,
    short* __restrict__ wq, short* __restrict__ bq,
    short* __restrict__ wp, float* __restrict__ bpo){
  const int tid = blockIdx.x*256 + threadIdx.x;
  const int nthr = gridDim.x*256;
  for (int i = tid; i < 768*256; i += nthr){
    float v = qkvw[i];
    if (i < 256*256) v *= 0.0625f;     // q rows scaled by c^-0.5
    wq[i] = f2bf(v);
  }
  for (int i = tid; i < 256*256; i += nthr) wp[i] = f2bf(pw[i]);
  if (tid < 768){ float v = qkvb[tid]; if (tid < 256) v *= 0.0625f; bq[tid] = f2bf(v); }
  if (tid < 256) bpo[tid] = pb[tid];
}

// ---------------- K1: groupnorm stats (mean, rstd per (b,g)) ---------------
__global__ __launch_bounds__(256) void gn_stats(const float* __restrict__ x,
                                                float* __restrict__ stats){
  const int bg = blockIdx.x;                 // 0..255 = b*32+g
  const float* p = x + (size_t)bg * 32768;   // 8 ch * 4096 contiguous
  const int t = threadIdx.x;
  float s1 = 0.f, s2 = 0.f;
  #pragma unroll
  for (int i = 0; i < 32; i++){
    f32x4 v = *(const f32x4*)(p + i*1024 + t*4);
    s1 += v[0]+v[1]+v[2]+v[3];
    s2 += v[0]*v[0]+v[1]*v[1]+v[2]*v[2]+v[3]*v[3];
  }
  #pragma unroll
  for (int off = 1; off < 64; off <<= 1){
    s1 += __shfl_xor(s1, off);
    s2 += __shfl_xor(s2, off);
  }
  __shared__ float a1[4], a2[4];
  const int w = t >> 6;
  if ((t & 63) == 0){ a1[w] = s1; a2[w] = s2; }
  __syncthreads();
  if (t == 0){
    float S1 = a1[0]+a1[1]+a1[2]+a1[3];
    float S2 = a2[0]+a2[1]+a2[2]+a2[3];
    float mu = S1 * (1.f/32768.f);
    float var = S2 * (1.f/32768.f) - mu*mu;
    stats[bg*2]   = mu;
    stats[bg*2+1] = rsqrtf(var + 1e-5f);
  }
}

// ---------------- K2: normalize + transpose -> h_t[b][n][c] bf16 -----------
__global__ __launch_bounds__(256) void gn_apply(
    const float* __restrict__ x, const float* __restrict__ stats,
    const float* __restrict__ nw, const float* __restrict__ nb,
    short* __restrict__ h_t){
  const int bx = blockIdx.x;
  const int b = bx >> 8; const int rem = bx & 255;
  const int ctile = rem >> 6, ntile = rem & 63;
  const int c0 = ctile << 6, n0 = ntile << 6;
  const int t = threadIdx.x;
  __shared__ short lt[64][72];
  {
    const int cl = t >> 2, nch = (t & 3) << 4;
    const int c = c0 + cl;
    const float mu   = stats[((b<<5) + (c>>3))*2];
    const float rstd = stats[((b<<5) + (c>>3))*2 + 1];
    const float A = rstd * nw[c];
    const float Bc = nb[c] - mu * A;
    const float* px = x + (((size_t)(b<<8) + c) << 12) + n0 + nch;
    #pragma unroll
    for (int j = 0; j < 4; j++){
      f32x4 v = *(const f32x4*)(px + j*4);
      lt[nch + j*4 + 0][cl] = f2bf(v[0]*A + Bc);
      lt[nch + j*4 + 1][cl] = f2bf(v[1]*A + Bc);
      lt[nch + j*4 + 2][cl] = f2bf(v[2]*A + Bc);
      lt[nch + j*4 + 3][cl] = f2bf(v[3]*A + Bc);
    }
  }
  __syncthreads();
  {
    const int nl = t >> 2, cch = (t & 3) << 4;
    s16x8 a0 = *(const s16x8*)&lt[nl][cch];
    s16x8 a1 = *(const s16x8*)&lt[nl][cch + 8];
    short* dst = h_t + (((size_t)(b<<12) + n0 + nl) << 8) + c0 + cch;
    *(s16x8*)dst = a0;
    *(s16x8*)(dst + 8) = a1;
  }
}

// ---------------- K3: qkv GEMM (bf16 MFMA, frags direct from global) -------
__global__ __launch_bounds__(256) void qkv_gemm(
    const short* __restrict__ h_t, const short* __restrict__ wq,
    const short* __restrict__ bq, short* __restrict__ q_t,
    short* __restrict__ k_t, short* __restrict__ v_buf){
  const int bx = blockIdx.x;
  const int b = bx / 768; const int rem = bx - b*768;
  const int nt = rem / 12, ot = rem - nt*12;
  const int n0 = nt << 6, co0 = ot << 6;
  const int t = threadIdx.x, w = t >> 6, lane = t & 63;
  const int lr = lane & 15, lg = lane >> 4;
  f32x4 acc[4] = { {0,0,0,0},{0,0,0,0},{0,0,0,0},{0,0,0,0} };
  if (co0 < 512){
    // q/k: M = n rows, N = out-channel cols
    const short* pa = h_t + (((size_t)b*4096 + n0 + w*16 + lr) << 8) + lg*8;
    #pragma unroll
    for (int kk = 0; kk < 8; kk++){
      bf16x8 a = ldb8(pa + kk*32);
      #pragma unroll
      for (int tt = 0; tt < 4; tt++){
        bf16x8 bb = ldb8(wq + (((size_t)(co0 + tt*16 + lr)) << 8) + kk*32 + lg*8);
        acc[tt] = __builtin_amdgcn_mfma_f32_16x16x32_bf16(a, bb, acc[tt], 0, 0, 0);
      }
    }
    #pragma unroll
    for (int tt = 0; tt < 4; tt++){
      const int col = co0 + tt*16 + lr;
      const float bias = bf2f(bq[col]);
      short* dst; int cc;
      if (col < 256){ dst = q_t; cc = col; } else { dst = k_t; cc = col - 256; }
      #pragma unroll
      for (int i = 0; i < 4; i++){
        const int row = n0 + w*16 + lg*4 + i;
        dst[(((size_t)b*4096 + row) << 8) + cc] = f2bf(acc[tt][i] + bias);
      }
    }
  } else {
    // v: swap roles -> M = out-channel rows, N = n cols -> natural [c][n] writes
    const short* pa = wq + (((size_t)(co0 + w*16 + lr)) << 8) + lg*8;
    #pragma unroll
    for (int kk = 0; kk < 8; kk++){
      bf16x8 a = ldb8(pa + kk*32);
      #pragma unroll
      for (int tt = 0; tt < 4; tt++){
        bf16x8 bb = ldb8(h_t + (((size_t)b*4096 + n0 + tt*16 + lr) << 8) + kk*32 + lg*8);
        acc[tt] = __builtin_amdgcn_mfma_f32_16x16x32_bf16(a, bb, acc[tt], 0, 0, 0);
      }
    }
    #pragma unroll
    for (int i = 0; i < 4; i++){
      const int co = co0 + w*16 + lg*4 + i;
      const float bias = bf2f(bq[co]);
      #pragma unroll
      for (int tt = 0; tt < 4; tt++){
        const int col = n0 + tt*16 + lr;
        v_buf[(((size_t)(b*256 + co - 512)) << 12) + col] = f2bf(acc[tt][i] + bias);
      }
    }
  }
}

// ======================= flash attention cores =============================
// Shared structure: 4 waves x 32 q (QB=128), KB=32, 32x32x16 MFMA,
// swapped QK^T in-register softmax, global_load_lds dbuf staging,
// K swizzle ^((key&15)<<4), V swizzle ^(((c>>1)&3)<<4).

#define ATTN_PROLOGUE(NKT)                                                   \
  const int t = threadIdx.x, w = t >> 6, l = t & 63;                         \
  const int lq = l & 31, hi = l >> 5;                                        \
  const int q0 = qt*128 + w*32;                                              \
  __shared__ short smem[32768];                                              \
  char* lds = (char*)smem;                                                   \
  bf16x8 qf[16];                                                             \
  {                                                                          \
    const short* pq = q_t + (((size_t)b*4096 + q0 + lq) << 8) + hi*8;        \
    _Pragma("unroll")                                                        \
    for (int ks = 0; ks < 16; ks++) qf[ks] = ldb8(pq + ks*16);               \
  }                                                                          \
  f32x16 of[8];                                                              \
  _Pragma("unroll")                                                          \
  for (int ct = 0; ct < 8; ct++)                                             \
    _Pragma("unroll")                                                        \
    for (int r = 0; r < 16; r++) of[ct][r] = 0.f;                            \
  float m_run = -1.0e30f, l_run = 0.f;                                       \
  const char* ksrc[4]; const char* vsrc[4];                                  \
  _Pragma("unroll")                                                          \
  for (int j = 0; j < 4; j++){                                               \
    const int key = w*8 + j*2 + hi;                                          \
    ksrc[j] = kbase + key*512 + (((l&31)*16) ^ ((key&15)<<4));               \
    const int c = w*64 + j*16 + (l>>2);                                      \
    vsrc[j] = vbase + (size_t)c*8192 + (((l&3)*16) ^ (((c>>1)&3)<<4));       \
  }

#define STAGE(buf, kt_) do {                                                 \
    _Pragma("unroll")                                                        \
    for (int j = 0; j < 4; j++)                                              \
      __builtin_amdgcn_global_load_lds(                                      \
        (const __attribute__((address_space(1))) unsigned*)(ksrc[j] + (size_t)(kt_)*16384), \
        (__attribute__((address_space(3))) unsigned*)(lds + (buf)*32768 + w*4096 + j*1024), \
        16, 0, 0);                                                           \
    _Pragma("unroll")                                                        \
    for (int j = 0; j < 4; j++)                                              \
      __builtin_amdgcn_global_load_lds(                                      \
        (const __attribute__((address_space(1))) unsigned*)(vsrc[j] + (size_t)(kt_)*64),    \
        (__attribute__((address_space(3))) unsigned*)(lds + (buf)*32768 + 16384 + w*4096 + j*1024), \
        16, 0, 0);                                                           \
  } while (0)

#define ATTN_TILE_BODY()                                                     \
    const char* Kb = lds + cur*32768;                                        \
    const char* Vb = lds + cur*32768 + 16384;                                \
    f32x16 sf;                                                               \
    _Pragma("unroll")                                                        \
    for (int r = 0; r < 16; r++) sf[r] = 0.f;                                \
    _Pragma("unroll")                                                        \
    for (int ks = 0; ks < 16; ks++){                                         \
      bf16x8 kf = ldb8((const short*)(Kb + (lq<<9) + ((ks*32 + hi16) ^ swzKr))); \
      sf = __builtin_amdgcn_mfma_f32_32x32x16_bf16(kf, qf[ks], sf, 0, 0, 0); \
    }                                                                        \
    float pm = sf[0];                                                        \
    _Pragma("unroll")                                                        \
    for (int r = 1; r < 16; r++) pm = fmaxf(pm, sf[r]);                      \
    pm = fmaxf(pm, __shfl_xor(pm, 32));                                      \
    if (!__all(pm <= m_run + 8.f)){                                          \
      const float mn = fmaxf(m_run, pm);                                     \
      const float corr = exp2f((m_run - mn) * LOG2E);                        \
      _Pragma("unroll")                                                      \
      for (int ct = 0; ct < 8; ct++)                                         \
        _Pragma("unroll")                                                    \
        for (int r = 0; r < 16; r++) of[ct][r] *= corr;                      \
      l_run *= corr;                                                         \
      m_run = mn;                                                            \
    }                                                                        \
    const float mL = m_run * LOG2E;                                          \
    float p[16]; float s = 0.f;                                              \
    _Pragma("unroll")                                                        \
    for (int r = 0; r < 16; r++){                                            \
      p[r] = exp2f(__builtin_fmaf(sf[r], LOG2E, -mL));                       \
      s += p[r];                                                             \
    }                                                                        \
    l_run += s + __shfl_xor(s, 32);                                          \
    unsigned own[8];                                                         \
    _Pragma("unroll")                                                        \
    for (int ks = 0; ks < 2; ks++){                                          \
      own[ks*4+0] = pk2(p[ks*8+0], p[ks*8+1]);                               \
      own[ks*4+1] = pk2(p[ks*8+2], p[ks*8+3]);                               \
      own[ks*4+2] = pk2(p[ks*8+4], p[ks*8+5]);                               \
      own[ks*4+3] = pk2(p[ks*8+6], p[ks*8+7]);                               \
    }                                                                        \
    unsigned prt[8];                                                         \
    _Pragma("unroll")                                                        \
    for (int i = 0; i < 8; i++) prt[i] = __shfl_xor(own[i], 32);             \
    bf16x8 pfrag[2];                                                         \
    _Pragma("unroll")                                                        \
    for (int ks = 0; ks < 2; ks++){                                          \
      union { unsigned u[4]; bf16x8 v; } uu;                                 \
      uu.u[0] = hi ? prt[ks*4+2] : own[ks*4+0];                              \
      uu.u[1] = hi ? prt[ks*4+3] : own[ks*4+1];                              \
      uu.u[2] = hi ? own[ks*4+2] : prt[ks*4+0];                              \
      uu.u[3] = hi ? own[ks*4+3] : prt[ks*4+1];                              \
      pfrag[ks] = uu.v;                                                      \
    }                                                                        \
    _Pragma("unroll")                                                        \
    for (int ks = 0; ks < 2; ks++){                                          \
      _Pragma("unroll")                                                      \
      for (int ct = 0; ct < 8; ct++){                                        \
        bf16x8 vf = ldb8((const short*)(Vb + ((ct*32 + lq)<<6) + ((ks*32 + hi16) ^ swzV))); \
        of[ct] = __builtin_amdgcn_mfma_f32_32x32x16_bf16(pfrag[ks], vf, of[ct], 0, 0, 0);   \
      }                                                                      \
    }

// ---------------- K4a: single-pass flash (fallback, grid 256) --------------
__global__ __launch_bounds__(256, 2) void attn_flash_full(
    const short* __restrict__ q_t, const short* __restrict__ k_t,
    const short* __restrict__ v_b, short* __restrict__ o_t){
  const int b  = blockIdx.x & 7;
  const int qt = blockIdx.x >> 3;
  const char* kbase = (const char*)(k_t + (((size_t)b*4096) << 8));
  const char* vbase = (const char*)(v_b + (((size_t)b*256) << 12));
  ATTN_PROLOGUE(128)
  STAGE(0, 0);
  __syncthreads();
  const int hi16 = hi*16;
  const int swzKr = (lq & 15) << 4;
  const int swzV  = ((lq >> 1) & 3) << 4;
  int cur = 0;
  for (int kt = 0; kt < 128; kt++){
    if (kt < 127) STAGE(cur^1, kt+1);
    ATTN_TILE_BODY()
    __syncthreads();
    cur ^= 1;
  }
  short* po = o_t + (((size_t)b*4096 + q0) << 8);
  #pragma unroll
  for (int r = 0; r < 16; r++){
    const int row = (r&3) + 8*(r>>2) + 4*hi;
    const float lv = __shfl(l_run, row);
    const float inv = __builtin_amdgcn_rcpf(lv);
    #pragma unroll
    for (int ct = 0; ct < 8; ct++){
      po[(size_t)row*256 + ct*32 + lq] = f2bf(of[ct][r] * inv);
    }
  }
}

// ---------------- K4b: split-K flash (grid 512 = 8b x 2kh x 32qt) ----------
__global__ __launch_bounds__(256, 2) void attn_flash_split(
    const short* __restrict__ q_t, const short* __restrict__ k_t,
    const short* __restrict__ v_b, short* __restrict__ oh0,
    short* __restrict__ oh1, float* __restrict__ ml){
  const int b  = blockIdx.x & 7;
  const int rest = blockIdx.x >> 3;
  const int kh = rest & 1;
  const int qt = rest >> 1;
  const char* kbase = (const char*)(k_t + (((size_t)b*4096 + kh*2048) << 8));
  const char* vbase = (const char*)(v_b + (((size_t)b*256) << 12) + kh*2048);
  ATTN_PROLOGUE(64)
  STAGE(0, 0);
  __syncthreads();
  const int hi16 = hi*16;
  const int swzKr = (lq & 15) << 4;
  const int swzV  = ((lq >> 1) & 3) << 4;
  int cur = 0;
  for (int kt = 0; kt < 64; kt++){
    if (kt < 63) STAGE(cur^1, kt+1);
    ATTN_TILE_BODY()
    __syncthreads();
    cur ^= 1;
  }
  short* ohp = kh ? oh1 : oh0;
  short* po = ohp + (((size_t)b*4096 + q0) << 8);
  #pragma unroll
  for (int r = 0; r < 16; r++){
    const int row = (r&3) + 8*(r>>2) + 4*hi;
    const float lv = __shfl(l_run, row);
    const float inv = __builtin_amdgcn_rcpf(lv);
    #pragma unroll
    for (int ct = 0; ct < 8; ct++){
      po[(size_t)row*256 + ct*32 + lq] = f2bf(of[ct][r] * inv);
    }
  }
  if (l < 32){
    const size_t mi = (((size_t)(kh*8 + b))*4096 + q0 + l)*2;
    ml[mi]   = m_run;
    ml[mi+1] = l_run;
  }
}

#undef STAGE
#undef ATTN_TILE_BODY
#undef ATTN_PROLOGUE

// ---------------- K4c: merge split-K halves --------------------------------
__global__ __launch_bounds__(256) void merge_halves(
    const short* __restrict__ oh0, const short* __restrict__ oh1,
    const float* __restrict__ ml, short* __restrict__ o_t){
  const int t = threadIdx.x;
  const int rr = blockIdx.x*16 + (t >> 4);     // global q-row 0..32767
  const int b = rr >> 12, q = rr & 4095;
  const size_t m0i = (((size_t)b)*4096 + q)*2;
  const size_t m1i = (((size_t)(8 + b))*4096 + q)*2;
  const float m0 = ml[m0i], l0 = ml[m0i+1];
  const float m1 = ml[m1i], l1 = ml[m1i+1];
  const float M  = fmaxf(m0, m1);
  const float w0 = l0 * exp2f((m0 - M) * LOG2E);
  const float w1 = l1 * exp2f((m1 - M) * LOG2E);
  const float inv = 1.f / (w0 + w1);
  const float a0 = w0 * inv, a1 = w1 * inv;
  const size_t base = (((size_t)rr) << 8) + ((t & 15) << 4);
  #pragma unroll
  for (int j = 0; j < 2; j++){
    s16x8 v0 = *(const s16x8*)(oh0 + base + j*8);
    s16x8 v1 = *(const s16x8*)(oh1 + base + j*8);
    s16x8 r;
    #pragma unroll
    for (int e = 0; e < 8; e++) r[e] = f2bf(a0*bf2f(v0[e]) + a1*bf2f(v1[e]));
    *(s16x8*)(o_t + base + j*8) = r;
  }
}

// ---------------- K5: proj GEMM + bias + residual --------------------------
__global__ __launch_bounds__(256) void proj_gemm(
    const short* __restrict__ o_t, const short* __restrict__ wp,
    const float* __restrict__ bp, const float* __restrict__ x,
    float* __restrict__ out){
  const int bx = blockIdx.x;
  const int b = bx >> 8; const int rem = bx & 255;
  const int ct = rem >> 6, qt = rem & 63;
  const int co0 = ct << 6, q0 = qt << 6;
  const int t = threadIdx.x, w = t >> 6, lane = t & 63;
  const int lr = lane & 15, lg = lane >> 4;
  f32x4 acc[4] = { {0,0,0,0},{0,0,0,0},{0,0,0,0},{0,0,0,0} };
  const short* pa = wp + (((size_t)(co0 + w*16 + lr)) << 8) + lg*8;
  #pragma unroll
  for (int kk = 0; kk < 8; kk++){
    bf16x8 a = ldb8(pa + kk*32);
    #pragma unroll
    for (int tt = 0; tt < 4; tt++){
      bf16x8 bb = ldb8(o_t + (((size_t)b*4096 + q0 + tt*16 + lr) << 8) + kk*32 + lg*8);
      acc[tt] = __builtin_amdgcn_mfma_f32_16x16x32_bf16(a, bb, acc[tt], 0, 0, 0);
    }
  }
  #pragma unroll
  for (int i = 0; i < 4; i++){
    const int co = co0 + w*16 + lg*4 + i;
    const float bias = bp[co];
    #pragma unroll
    for (int tt = 0; tt < 4; tt++){
      const int q = q0 + tt*16 + lr;
      const size_t idx = (((size_t)(b*256 + co)) << 12) + q;
      out[idx] = acc[tt][i] + bias + x[idx];
    }
  }
}

// ---------------- workspace layout -----------------------------------------
static constexpr size_t SZT  = (size_t)8 * 4096 * 256 * 2;  // 16 MB bf16 tensor
static constexpr size_t OFF_STATS = 0;                      // 2 KB
static constexpr size_t OFF_WQ = 4096;                      // 768*256*2
static constexpr size_t OFF_BQ = OFF_WQ + 768*256*2;
static constexpr size_t OFF_WP = OFF_BQ + 768*2;
static constexpr size_t OFF_BP = OFF_WP + 256*256*2;
static constexpr size_t OFF_HT = 532480;                    // also oh0 (ht dead post-qkv)
static constexpr size_t OFF_QT = OFF_HT + SZT;
static constexpr size_t OFF_KT = OFF_QT + SZT;
static constexpr size_t OFF_V  = OFF_KT + SZT;
static constexpr size_t OFF_OT = OFF_V + SZT;
static constexpr size_t OFF_OH1 = OFF_OT + SZT;
static constexpr size_t OFF_ML  = OFF_OH1 + SZT;
static constexpr size_t WS_NEED_SPLIT = OFF_ML + (size_t)2*8*4096*2*4;

extern "C" void kernel_launch(void* const* d_in, const int* in_sizes, int n_in,
                              void* d_out, int out_size, void* d_ws, size_t ws_size,
                              hipStream_t stream){
  const float* x    = (const float*)d_in[0];
  const float* nw   = (const float*)d_in[1];
  const float* nb   = (const float*)d_in[2];
  const float* qkvw = (const float*)d_in[3];
  const float* qkvb = (const float*)d_in[4];
  const float* pw   = (const float*)d_in[5];
  const float* pb   = (const float*)d_in[6];
  float* out = (float*)d_out;
  char* ws = (char*)d_ws;

  float* stats = (float*)(ws + OFF_STATS);
  short* wq    = (short*)(ws + OFF_WQ);
  short* bq    = (short*)(ws + OFF_BQ);
  short* wp    = (short*)(ws + OFF_WP);
  float* bp    = (float*)(ws + OFF_BP);
  short* ht    = (short*)(ws + OFF_HT);
  short* qt    = (short*)(ws + OFF_QT);
  short* kt    = (short*)(ws + OFF_KT);
  short* vb    = (short*)(ws + OFF_V);
  short* ot    = (short*)(ws + OFF_OT);
  short* oh1   = (short*)(ws + OFF_OH1);
  float* ml    = (float*)(ws + OFF_ML);

  prep_w   <<<256,  256, 0, stream>>>(qkvw, qkvb, pw, pb, wq, bq, wp, bp);
  gn_stats <<<256,  256, 0, stream>>>(x, stats);
  gn_apply <<<2048, 256, 0, stream>>>(x, stats, nw, nb, ht);
  qkv_gemm <<<6144, 256, 0, stream>>>(ht, wq, bq, qt, kt, vb);
  if (ws_size >= WS_NEED_SPLIT){
    attn_flash_split<<<512, 256, 0, stream>>>(qt, kt, vb, ht, oh1, ml);
    merge_halves    <<<2048, 256, 0, stream>>>(ht, oh1, ml, ot);
  } else {
    attn_flash_full <<<256, 256, 0, stream>>>(qt, kt, vb, ot);
  }
  proj_gemm<<<2048, 256, 0, stream>>>(ot, wp, bp, x, out);
}

// Round 5
// 406.006 us; speedup vs baseline: 1.4307x; 1.0214x over previous
//
#include <hip/hip_runtime.h>

typedef __attribute__((ext_vector_type(4))) float f32x4;
typedef __attribute__((ext_vector_type(16))) float f32x16;
typedef __attribute__((ext_vector_type(8))) __bf16 bf16x8;
typedef __attribute__((ext_vector_type(8))) short s16x8;

__device__ __forceinline__ short f2bf(float f){
  union { float f; unsigned u; } v; v.f = f;
  unsigned r = v.u + 0x7fffu + ((v.u >> 16) & 1u);
  return (short)(r >> 16);
}
__device__ __forceinline__ float bf2f(short h){
  union { unsigned u; float f; } v; v.u = ((unsigned)(unsigned short)h) << 16; return v.f;
}
__device__ __forceinline__ bf16x8 ldb8(const short* p){ return *(const bf16x8*)p; }
__device__ __forceinline__ unsigned pk2(float a, float b){
  return (unsigned)(unsigned short)f2bf(a) | ((unsigned)(unsigned short)f2bf(b) << 16);
}

#define LOG2E 1.4426950408889634f

// ---------------- K0: weight prep (fp32 -> bf16, fold 1/16 into q rows) ----
__global__ __launch_bounds__(256) void prep_w(
    const float* __restrict__ qkvw, const float* __restrict__ qkvb,
    const float* __restrict__ pw, const float* __restrict__ pb,
    short* __restrict__ wq, short* __restrict__ bq,
    short* __restrict__ wp, float* __restrict__ bpo){
  const int tid = blockIdx.x*256 + threadIdx.x;
  const int nthr = gridDim.x*256;
  for (int i = tid; i < 768*256; i += nthr){
    float v = qkvw[i];
    if (i < 256*256) v *= 0.0625f;     // q rows scaled by c^-0.5
    wq[i] = f2bf(v);
  }
  for (int i = tid; i < 256*256; i += nthr) wp[i] = f2bf(pw[i]);
  if (tid < 768){ float v = qkvb[tid]; if (tid < 256) v *= 0.0625f; bq[tid] = f2bf(v); }
  if (tid < 256) bpo[tid] = pb[tid];
}

// ---------------- K1: groupnorm stats (mean, rstd per (b,g)) ---------------
__global__ __launch_bounds__(256) void gn_stats(const float* __restrict__ x,
                                                float* __restrict__ stats){
  const int bg = blockIdx.x;                 // 0..255 = b*32+g
  const float* p = x + (size_t)bg * 32768;   // 8 ch * 4096 contiguous
  const int t = threadIdx.x;
  float s1 = 0.f, s2 = 0.f;
  #pragma unroll
  for (int i = 0; i < 32; i++){
    f32x4 v = *(const f32x4*)(p + i*1024 + t*4);
    s1 += v[0]+v[1]+v[2]+v[3];
    s2 += v[0]*v[0]+v[1]*v[1]+v[2]*v[2]+v[3]*v[3];
  }
  #pragma unroll
  for (int off = 1; off < 64; off <<= 1){
    s1 += __shfl_xor(s1, off);
    s2 += __shfl_xor(s2, off);
  }
  __shared__ float a1[4], a2[4];
  const int w = t >> 6;
  if ((t & 63) == 0){ a1[w] = s1; a2[w] = s2; }
  __syncthreads();
  if (t == 0){
    float S1 = a1[0]+a1[1]+a1[2]+a1[3];
    float S2 = a2[0]+a2[1]+a2[2]+a2[3];
    float mu = S1 * (1.f/32768.f);
    float var = S2 * (1.f/32768.f) - mu*mu;
    stats[bg*2]   = mu;
    stats[bg*2+1] = rsqrtf(var + 1e-5f);
  }
}

// ---------------- K2: normalize + transpose -> h_t[b][n][c] bf16 -----------
__global__ __launch_bounds__(256) void gn_apply(
    const float* __restrict__ x, const float* __restrict__ stats,
    const float* __restrict__ nw, const float* __restrict__ nb,
    short* __restrict__ h_t){
  const int bx = blockIdx.x;
  const int b = bx >> 8; const int rem = bx & 255;
  const int ctile = rem >> 6, ntile = rem & 63;
  const int c0 = ctile << 6, n0 = ntile << 6;
  const int t = threadIdx.x;
  __shared__ short lt[64][72];
  {
    const int cl = t >> 2, nch = (t & 3) << 4;
    const int c = c0 + cl;
    const float mu   = stats[((b<<5) + (c>>3))*2];
    const float rstd = stats[((b<<5) + (c>>3))*2 + 1];
    const float A = rstd * nw[c];
    const float Bc = nb[c] - mu * A;
    const float* px = x + (((size_t)(b<<8) + c) << 12) + n0 + nch;
    #pragma unroll
    for (int j = 0; j < 4; j++){
      f32x4 v = *(const f32x4*)(px + j*4);
      lt[nch + j*4 + 0][cl] = f2bf(v[0]*A + Bc);
      lt[nch + j*4 + 1][cl] = f2bf(v[1]*A + Bc);
      lt[nch + j*4 + 2][cl] = f2bf(v[2]*A + Bc);
      lt[nch + j*4 + 3][cl] = f2bf(v[3]*A + Bc);
    }
  }
  __syncthreads();
  {
    const int nl = t >> 2, cch = (t & 3) << 4;
    s16x8 a0 = *(const s16x8*)&lt[nl][cch];
    s16x8 a1 = *(const s16x8*)&lt[nl][cch + 8];
    short* dst = h_t + (((size_t)(b<<12) + n0 + nl) << 8) + c0 + cch;
    *(s16x8*)dst = a0;
    *(s16x8*)(dst + 8) = a1;
  }
}

// ---------------- K3a: q/k GEMM — A-frags in regs, full 512-col sweep ------
__global__ __launch_bounds__(256) void qkv_qk(
    const short* __restrict__ h_t, const short* __restrict__ wq,
    const short* __restrict__ bq, short* __restrict__ q_t,
    short* __restrict__ k_t){
  const int b = blockIdx.x >> 6, nt = blockIdx.x & 63;
  const int n0 = nt << 6;
  const int t = threadIdx.x, w = t >> 6, lane = t & 63;
  const int lr = lane & 15, lg = lane >> 4;
  bf16x8 a[8];
  {
    const short* pa = h_t + (((size_t)b*4096 + n0 + w*16 + lr) << 8) + lg*8;
    #pragma unroll
    for (int kk = 0; kk < 8; kk++) a[kk] = ldb8(pa + kk*32);
  }
  for (int ot = 0; ot < 8; ot++){
    const int co0 = ot << 6;
    f32x4 acc[4] = { {0,0,0,0},{0,0,0,0},{0,0,0,0},{0,0,0,0} };
    #pragma unroll
    for (int kk = 0; kk < 8; kk++){
      #pragma unroll
      for (int tt = 0; tt < 4; tt++){
        bf16x8 bb = ldb8(wq + (((size_t)(co0 + tt*16 + lr)) << 8) + kk*32 + lg*8);
        acc[tt] = __builtin_amdgcn_mfma_f32_16x16x32_bf16(a[kk], bb, acc[tt], 0, 0, 0);
      }
    }
    short* dst = (ot < 4) ? q_t : k_t;
    const int cb = (ot < 4) ? co0 : co0 - 256;
    #pragma unroll
    for (int tt = 0; tt < 4; tt++){
      const float bias = bf2f(bq[co0 + tt*16 + lr]);
      #pragma unroll
      for (int i = 0; i < 4; i++){
        const int row = n0 + w*16 + lg*4 + i;
        dst[(((size_t)b*4096 + row) << 8) + cb + tt*16 + lr] = f2bf(acc[tt][i] + bias);
      }
    }
  }
}

// ---------------- K3b: v GEMM (swapped roles) — W-frags in regs ------------
__global__ __launch_bounds__(256) void qkv_v(
    const short* __restrict__ h_t, const short* __restrict__ wq,
    const short* __restrict__ bq, short* __restrict__ v_buf){
  const int b = blockIdx.x >> 5; const int rem = blockIdx.x & 31;
  const int cot = rem >> 3, nt2 = rem & 7;
  const int co0 = 512 + (cot << 6), n0 = nt2 << 9;
  const int t = threadIdx.x, w = t >> 6, lane = t & 63;
  const int lr = lane & 15, lg = lane >> 4;
  bf16x8 a[8];
  {
    const short* pa = wq + (((size_t)(co0 + w*16 + lr)) << 8) + lg*8;
    #pragma unroll
    for (int kk = 0; kk < 8; kk++) a[kk] = ldb8(pa + kk*32);
  }
  for (int st = 0; st < 8; st++){
    const int ns = n0 + (st << 6);
    f32x4 acc[4] = { {0,0,0,0},{0,0,0,0},{0,0,0,0},{0,0,0,0} };
    #pragma unroll
    for (int kk = 0; kk < 8; kk++){
      #pragma unroll
      for (int tt = 0; tt < 4; tt++){
        bf16x8 bb = ldb8(h_t + (((size_t)b*4096 + ns + tt*16 + lr) << 8) + kk*32 + lg*8);
        acc[tt] = __builtin_amdgcn_mfma_f32_16x16x32_bf16(a[kk], bb, acc[tt], 0, 0, 0);
      }
    }
    #pragma unroll
    for (int i = 0; i < 4; i++){
      const int co = co0 + w*16 + lg*4 + i;
      const float bias = bf2f(bq[co]);
      #pragma unroll
      for (int tt = 0; tt < 4; tt++){
        v_buf[(((size_t)(b*256 + co - 512)) << 12) + ns + tt*16 + lr] = f2bf(acc[tt][i] + bias);
      }
    }
  }
}

// ======================= flash attention (counted-vmcnt) ===================
// 4 waves x 32 q (QB=128), KB=32, 32x32x16 MFMA, swapped QK^T softmax,
// global_load_lds dbuf; T4 schedule: STAGE(next) -> vmcnt(8) -> s_barrier ->
// compute -> s_barrier. Prefetch loads stay in flight across barriers.
template<int NKH>
__global__ __launch_bounds__(256, 2) void attn_flash_t(
    const short* __restrict__ q_t, const short* __restrict__ k_t,
    const short* __restrict__ v_b, short* __restrict__ o0,
    short* __restrict__ o1, float* __restrict__ ml){
  constexpr int NT = 128 / NKH;
  const int b = blockIdx.x & 7;
  const int rest = blockIdx.x >> 3;
  const int kh = rest & (NKH - 1);
  const int qt = rest / NKH;
  const char* kbase = (const char*)(k_t + (((size_t)b*4096 + kh*NT*32) << 8));
  const char* vbase = (const char*)(v_b + (((size_t)b*256) << 12) + (size_t)kh*NT*32);

  const int t = threadIdx.x, w = t >> 6, l = t & 63;
  const int lq = l & 31, hi = l >> 5;
  const int q0 = qt*128 + w*32;

  __shared__ short smem[32768];   // 64 KB: [buf2][K 16KB | V 16KB]
  char* lds = (char*)smem;

  bf16x8 qf[16];
  {
    const short* pq = q_t + (((size_t)b*4096 + q0 + lq) << 8) + hi*8;
    #pragma unroll
    for (int ks = 0; ks < 16; ks++) qf[ks] = ldb8(pq + ks*16);
  }
  f32x16 of[8];
  #pragma unroll
  for (int ct = 0; ct < 8; ct++)
    #pragma unroll
    for (int r = 0; r < 16; r++) of[ct][r] = 0.f;
  float m_run = -1.0e30f, l_run = 0.f;

  const char* ksrc[4]; const char* vsrc[4];
  #pragma unroll
  for (int j = 0; j < 4; j++){
    const int key = w*8 + j*2 + hi;
    ksrc[j] = kbase + key*512 + (((l&31)*16) ^ ((key&15)<<4));
    const int c = w*64 + j*16 + (l>>2);
    vsrc[j] = vbase + (size_t)c*8192 + (((l&3)*16) ^ (((c>>1)&3)<<4));
  }

  #define STAGE(buf, kt_) do {                                               \
    _Pragma("unroll")                                                        \
    for (int j = 0; j < 4; j++)                                              \
      __builtin_amdgcn_global_load_lds(                                      \
        (const __attribute__((address_space(1))) unsigned*)(ksrc[j] + (size_t)(kt_)*16384), \
        (__attribute__((address_space(3))) unsigned*)(lds + (buf)*32768 + w*4096 + j*1024), \
        16, 0, 0);                                                           \
    _Pragma("unroll")                                                        \
    for (int j = 0; j < 4; j++)                                              \
      __builtin_amdgcn_global_load_lds(                                      \
        (const __attribute__((address_space(1))) unsigned*)(vsrc[j] + (size_t)(kt_)*64),    \
        (__attribute__((address_space(3))) unsigned*)(lds + (buf)*32768 + 16384 + w*4096 + j*1024), \
        16, 0, 0);                                                           \
  } while (0)

  STAGE(0, 0);

  const int hi16 = hi*16;
  const int swzKr = (lq & 15) << 4;
  const int swzV  = ((lq >> 1) & 3) << 4;
  int cur = 0;

  for (int kt2 = 0; kt2 < NT; kt2++){
    if (kt2 + 1 < NT){
      STAGE(cur^1, kt2+1);
      asm volatile("s_waitcnt vmcnt(8)" ::: "memory");   // tile kt2 landed (own)
    } else {
      asm volatile("s_waitcnt vmcnt(0)" ::: "memory");
    }
    __builtin_amdgcn_s_barrier();                        // all waves' tile landed
    const char* Kb = lds + cur*32768;
    const char* Vb = lds + cur*32768 + 16384;

    // ---- S^T = mfma(K, Q) ----
    f32x16 sf;
    #pragma unroll
    for (int r = 0; r < 16; r++) sf[r] = 0.f;
    __builtin_amdgcn_s_setprio(1);
    #pragma unroll
    for (int ks = 0; ks < 16; ks++){
      bf16x8 kf = ldb8((const short*)(Kb + (lq<<9) + ((ks*32 + hi16) ^ swzKr)));
      sf = __builtin_amdgcn_mfma_f32_32x32x16_bf16(kf, qf[ks], sf, 0, 0, 0);
    }
    __builtin_amdgcn_s_setprio(0);

    // ---- online softmax, in-register (lane pair l <-> l^32) ----
    float pm = sf[0];
    #pragma unroll
    for (int r = 1; r < 16; r++) pm = fmaxf(pm, sf[r]);
    pm = fmaxf(pm, __shfl_xor(pm, 32));
    if (!__all(pm <= m_run + 8.f)){          // defer-max (THR=8)
      const float mn = fmaxf(m_run, pm);
      const float corr = exp2f((m_run - mn) * LOG2E);
      #pragma unroll
      for (int ct = 0; ct < 8; ct++)
        #pragma unroll
        for (int r = 0; r < 16; r++) of[ct][r] *= corr;
      l_run *= corr;
      m_run = mn;
    }
    const float mL = m_run * LOG2E;
    float p[16]; float s = 0.f;
    #pragma unroll
    for (int r = 0; r < 16; r++){
      p[r] = exp2f(__builtin_fmaf(sf[r], LOG2E, -mL));
      s += p[r];
    }
    l_run += s + __shfl_xor(s, 32);

    // ---- pack P -> bf16 A-frags (exchange halves with lane^32) ----
    unsigned own[8];
    #pragma unroll
    for (int ks = 0; ks < 2; ks++){
      own[ks*4+0] = pk2(p[ks*8+0], p[ks*8+1]);
      own[ks*4+1] = pk2(p[ks*8+2], p[ks*8+3]);
      own[ks*4+2] = pk2(p[ks*8+4], p[ks*8+5]);
      own[ks*4+3] = pk2(p[ks*8+6], p[ks*8+7]);
    }
    unsigned prt[8];
    #pragma unroll
    for (int i = 0; i < 8; i++) prt[i] = __shfl_xor(own[i], 32);
    bf16x8 pfrag[2];
    #pragma unroll
    for (int ks = 0; ks < 2; ks++){
      union { unsigned u[4]; bf16x8 v; } uu;
      uu.u[0] = hi ? prt[ks*4+2] : own[ks*4+0];
      uu.u[1] = hi ? prt[ks*4+3] : own[ks*4+1];
      uu.u[2] = hi ? own[ks*4+2] : prt[ks*4+0];
      uu.u[3] = hi ? own[ks*4+3] : prt[ks*4+1];
      pfrag[ks] = uu.v;
    }

    // ---- PV ----
    __builtin_amdgcn_s_setprio(1);
    #pragma unroll
    for (int ks = 0; ks < 2; ks++){
      #pragma unroll
      for (int ct = 0; ct < 8; ct++){
        bf16x8 vf = ldb8((const short*)(Vb + ((ct*32 + lq)<<6) + ((ks*32 + hi16) ^ swzV)));
        of[ct] = __builtin_amdgcn_mfma_f32_32x32x16_bf16(pfrag[ks], vf, of[ct], 0, 0, 0);
      }
    }
    __builtin_amdgcn_s_setprio(0);
    __builtin_amdgcn_s_barrier();            // reads done -> buffer reusable
    cur ^= 1;
  }
  #undef STAGE

  short* ohp;
  if constexpr (NKH == 1) ohp = o0; else ohp = kh ? o1 : o0;
  short* po = ohp + (((size_t)b*4096 + q0) << 8);
  #pragma unroll
  for (int r = 0; r < 16; r++){
    const int row = (r&3) + 8*(r>>2) + 4*hi;
    const float lv = __shfl(l_run, row);
    const float inv = __builtin_amdgcn_rcpf(lv);
    #pragma unroll
    for (int ct = 0; ct < 8; ct++){
      po[(size_t)row*256 + ct*32 + lq] = f2bf(of[ct][r] * inv);
    }
  }
  if constexpr (NKH > 1){
    if (l < 32){
      const size_t mi = (((size_t)(kh*8 + b))*4096 + q0 + l)*2;
      ml[mi]   = m_run;
      ml[mi+1] = l_run;
    }
  }
}

// ---------------- K4c: merge split-K halves --------------------------------
__global__ __launch_bounds__(256) void merge_halves(
    const short* __restrict__ oh0, const short* __restrict__ oh1,
    const float* __restrict__ ml, short* __restrict__ o_t){
  const int t = threadIdx.x;
  const int rr = blockIdx.x*16 + (t >> 4);     // global q-row 0..32767
  const int b = rr >> 12, q = rr & 4095;
  const size_t m0i = (((size_t)b)*4096 + q)*2;
  const size_t m1i = (((size_t)(8 + b))*4096 + q)*2;
  const float m0 = ml[m0i], l0 = ml[m0i+1];
  const float m1 = ml[m1i], l1 = ml[m1i+1];
  const float M  = fmaxf(m0, m1);
  const float w0 = l0 * exp2f((m0 - M) * LOG2E);
  const float w1 = l1 * exp2f((m1 - M) * LOG2E);
  const float inv = 1.f / (w0 + w1);
  const float a0 = w0 * inv, a1 = w1 * inv;
  const size_t base = (((size_t)rr) << 8) + ((t & 15) << 4);
  #pragma unroll
  for (int j = 0; j < 2; j++){
    s16x8 v0 = *(const s16x8*)(oh0 + base + j*8);
    s16x8 v1 = *(const s16x8*)(oh1 + base + j*8);
    s16x8 r;
    #pragma unroll
    for (int e = 0; e < 8; e++) r[e] = f2bf(a0*bf2f(v0[e]) + a1*bf2f(v1[e]));
    *(s16x8*)(o_t + base + j*8) = r;
  }
}

// ---------------- K5: proj GEMM + bias + residual (o_t read once) ----------
__global__ __launch_bounds__(256) void proj_gemm(
    const short* __restrict__ o_t, const short* __restrict__ wp,
    const float* __restrict__ bp, const float* __restrict__ x,
    float* __restrict__ out){
  const int b = blockIdx.x >> 6, qt = blockIdx.x & 63;
  const int q0 = qt << 6;
  const int t = threadIdx.x, w = t >> 6, lane = t & 63;
  const int lr = lane & 15, lg = lane >> 4;
  f32x4 acc[4][4];
  #pragma unroll
  for (int cg = 0; cg < 4; cg++)
    #pragma unroll
    for (int tt = 0; tt < 4; tt++) acc[cg][tt] = (f32x4){0.f,0.f,0.f,0.f};
  #pragma unroll
  for (int kk = 0; kk < 8; kk++){
    bf16x8 bfr[4];
    #pragma unroll
    for (int tt = 0; tt < 4; tt++)
      bfr[tt] = ldb8(o_t + (((size_t)b*4096 + q0 + tt*16 + lr) << 8) + kk*32 + lg*8);
    #pragma unroll
    for (int cg = 0; cg < 4; cg++){
      bf16x8 af = ldb8(wp + (((size_t)(cg*64 + w*16 + lr)) << 8) + kk*32 + lg*8);
      #pragma unroll
      for (int tt = 0; tt < 4; tt++)
        acc[cg][tt] = __builtin_amdgcn_mfma_f32_16x16x32_bf16(af, bfr[tt], acc[cg][tt], 0, 0, 0);
    }
  }
  #pragma unroll
  for (int cg = 0; cg < 4; cg++){
    #pragma unroll
    for (int i = 0; i < 4; i++){
      const int co = cg*64 + w*16 + lg*4 + i;
      const float bias = bp[co];
      #pragma unroll
      for (int tt = 0; tt < 4; tt++){
        const int q = q0 + tt*16 + lr;
        const size_t idx = (((size_t)(b*256 + co)) << 12) + q;
        out[idx] = acc[cg][tt][i] + bias + x[idx];
      }
    }
  }
}

// ---------------- workspace layout (unchanged, proven) ---------------------
static constexpr size_t SZT  = (size_t)8 * 4096 * 256 * 2;  // 16 MB bf16 tensor
static constexpr size_t OFF_STATS = 0;                      // 2 KB
static constexpr size_t OFF_WQ = 4096;
static constexpr size_t OFF_BQ = OFF_WQ + 768*256*2;
static constexpr size_t OFF_WP = OFF_BQ + 768*2;
static constexpr size_t OFF_BP = OFF_WP + 256*256*2;
static constexpr size_t OFF_HT = 532480;                    // also oh0 (ht dead post-qkv)
static constexpr size_t OFF_QT = OFF_HT + SZT;
static constexpr size_t OFF_KT = OFF_QT + SZT;
static constexpr size_t OFF_V  = OFF_KT + SZT;
static constexpr size_t OFF_OT = OFF_V + SZT;
static constexpr size_t OFF_OH1 = OFF_OT + SZT;
static constexpr size_t OFF_ML  = OFF_OH1 + SZT;
static constexpr size_t WS_NEED_SPLIT = OFF_ML + (size_t)2*8*4096*2*4;

extern "C" void kernel_launch(void* const* d_in, const int* in_sizes, int n_in,
                              void* d_out, int out_size, void* d_ws, size_t ws_size,
                              hipStream_t stream){
  const float* x    = (const float*)d_in[0];
  const float* nw   = (const float*)d_in[1];
  const float* nb   = (const float*)d_in[2];
  const float* qkvw = (const float*)d_in[3];
  const float* qkvb = (const float*)d_in[4];
  const float* pw   = (const float*)d_in[5];
  const float* pb   = (const float*)d_in[6];
  float* out = (float*)d_out;
  char* ws = (char*)d_ws;

  float* stats = (float*)(ws + OFF_STATS);
  short* wq    = (short*)(ws + OFF_WQ);
  short* bq    = (short*)(ws + OFF_BQ);
  short* wp    = (short*)(ws + OFF_WP);
  float* bp    = (float*)(ws + OFF_BP);
  short* ht    = (short*)(ws + OFF_HT);
  short* qt    = (short*)(ws + OFF_QT);
  short* kt    = (short*)(ws + OFF_KT);
  short* vb    = (short*)(ws + OFF_V);
  short* ot    = (short*)(ws + OFF_OT);
  short* oh1   = (short*)(ws + OFF_OH1);
  float* ml    = (float*)(ws + OFF_ML);

  prep_w   <<<256,  256, 0, stream>>>(qkvw, qkvb, pw, pb, wq, bq, wp, bp);
  gn_stats <<<256,  256, 0, stream>>>(x, stats);
  gn_apply <<<2048, 256, 0, stream>>>(x, stats, nw, nb, ht);
  qkv_qk   <<<512,  256, 0, stream>>>(ht, wq, bq, qt, kt);
  qkv_v    <<<256,  256, 0, stream>>>(ht, wq, bq, vb);
  if (ws_size >= WS_NEED_SPLIT){
    attn_flash_t<2><<<512, 256, 0, stream>>>(qt, kt, vb, ht, oh1, ml);
    merge_halves   <<<2048, 256, 0, stream>>>(ht, oh1, ml, ot);
  } else {
    attn_flash_t<1><<<256, 256, 0, stream>>>(qt, kt, vb, ot, ot, ml);
  }
  proj_gemm<<<512, 256, 0, stream>>>(ot, wp, bp, x, out);
}

// Round 6
// 313.123 us; speedup vs baseline: 1.8551x; 1.2966x over previous
//
#include <hip/hip_runtime.h>

typedef __attribute__((ext_vector_type(4))) float f32x4;
typedef __attribute__((ext_vector_type(16))) float f32x16;
typedef __attribute__((ext_vector_type(8))) __bf16 bf16x8;
typedef __attribute__((ext_vector_type(8))) short s16x8;

__device__ __forceinline__ short f2bf(float f){
  union { __bf16 h; short s; } v; v.h = (__bf16)f; return v.s;
}
__device__ __forceinline__ float bf2f(short h){
  union { unsigned u; float f; } v; v.u = ((unsigned)(unsigned short)h) << 16; return v.f;
}
__device__ __forceinline__ bf16x8 ldb8(const short* p){ return *(const bf16x8*)p; }
__device__ __forceinline__ unsigned pk2(float a, float b){
  union { __bf16 h[2]; unsigned u; } v; v.h[0] = (__bf16)a; v.h[1] = (__bf16)b; return v.u;
}

#define LOG2E 1.4426950408889634f

// ---------------- K0: weight prep (fp32 -> bf16, fold 1/16 into q rows) ----
__global__ __launch_bounds__(256) void prep_w(
    const float* __restrict__ qkvw, const float* __restrict__ qkvb,
    const float* __restrict__ pw, const float* __restrict__ pb,
    short* __restrict__ wq, short* __restrict__ bq,
    short* __restrict__ wp, float* __restrict__ bpo){
  const int tid = blockIdx.x*256 + threadIdx.x;
  const int nthr = gridDim.x*256;
  for (int i = tid; i < 768*256; i += nthr){
    float v = qkvw[i];
    if (i < 256*256) v *= 0.0625f;     // q rows scaled by c^-0.5
    wq[i] = f2bf(v);
  }
  for (int i = tid; i < 256*256; i += nthr) wp[i] = f2bf(pw[i]);
  if (tid < 768){ float v = qkvb[tid]; if (tid < 256) v *= 0.0625f; bq[tid] = f2bf(v); }
  if (tid < 256) bpo[tid] = pb[tid];
}

// ---------------- K1: groupnorm stats (mean, rstd per (b,g)) ---------------
__global__ __launch_bounds__(256) void gn_stats(const float* __restrict__ x,
                                                float* __restrict__ stats){
  const int bg = blockIdx.x;                 // 0..255 = b*32+g
  const float* p = x + (size_t)bg * 32768;   // 8 ch * 4096 contiguous
  const int t = threadIdx.x;
  float s1 = 0.f, s2 = 0.f;
  #pragma unroll
  for (int i = 0; i < 32; i++){
    f32x4 v = *(const f32x4*)(p + i*1024 + t*4);
    s1 += v[0]+v[1]+v[2]+v[3];
    s2 += v[0]*v[0]+v[1]*v[1]+v[2]*v[2]+v[3]*v[3];
  }
  #pragma unroll
  for (int off = 1; off < 64; off <<= 1){
    s1 += __shfl_xor(s1, off);
    s2 += __shfl_xor(s2, off);
  }
  __shared__ float a1[4], a2[4];
  const int w = t >> 6;
  if ((t & 63) == 0){ a1[w] = s1; a2[w] = s2; }
  __syncthreads();
  if (t == 0){
    float S1 = a1[0]+a1[1]+a1[2]+a1[3];
    float S2 = a2[0]+a2[1]+a2[2]+a2[3];
    float mu = S1 * (1.f/32768.f);
    float var = S2 * (1.f/32768.f) - mu*mu;
    stats[bg*2]   = mu;
    stats[bg*2+1] = rsqrtf(var + 1e-5f);
  }
}

// ---------------- K2: fused groupnorm-apply + qkv GEMM ---------------------
// Block = (b, 64 n-rows). Phase 1: normalize x-tile -> swizzled LDS h[64][256]
// (short col sc = c ^ ((n&7)<<3), bank-conflict-free b128 reads). Phase 2:
// 64n x 768co x 256k GEMM; wave w sweeps co chunks {w*64, 256+w*64, 512+w*64}
// (one q, one k, one v chunk); v chunk uses swapped operands -> [c][n] writes.
__global__ __launch_bounds__(256) void gn_qkv(
    const float* __restrict__ x, const float* __restrict__ stats,
    const float* __restrict__ nw, const float* __restrict__ nb,
    const short* __restrict__ wq, const short* __restrict__ bq,
    short* __restrict__ q_t, short* __restrict__ k_t,
    short* __restrict__ v_buf){
  const int b = blockIdx.x >> 6, nt = blockIdx.x & 63;
  const int n0 = nt << 6;
  const int t = threadIdx.x, w = t >> 6, lane = t & 63;
  const int lr = lane & 15, lg = lane >> 4;
  __shared__ short lt[64*256];   // 32 KB

  // phase 1: x[b][c][n0..n0+64] -> normalized bf16, transposed into LDS
  {
    const int nq = (t & 3) << 4;           // 16-n chunk per thread
    #pragma unroll
    for (int pass = 0; pass < 4; pass++){
      const int c = (t >> 2) + pass*64;
      const float mu   = stats[((b<<5) + (c>>3))*2];
      const float rstd = stats[((b<<5) + (c>>3))*2 + 1];
      const float A = rstd * nw[c];
      const float Bc = nb[c] - mu*A;
      const float* px = x + (((size_t)(b<<8) + c) << 12) + n0 + nq;
      #pragma unroll
      for (int j4 = 0; j4 < 4; j4++){
        f32x4 v = *(const f32x4*)(px + j4*4);
        #pragma unroll
        for (int e = 0; e < 4; e++){
          const int n = nq + j4*4 + e;
          lt[n*256 + (c ^ ((n&7)<<3))] = f2bf(v[e]*A + Bc);
        }
      }
    }
  }
  __syncthreads();

  // phase 2: GEMM
  for (int ch = 0; ch < 3; ch++){
    const int co0 = w*64 + ch*256;
    f32x4 acc[4][4];
    #pragma unroll
    for (int ct = 0; ct < 4; ct++)
      #pragma unroll
      for (int tt = 0; tt < 4; tt++) acc[ct][tt] = (f32x4){0.f,0.f,0.f,0.f};
    #pragma unroll
    for (int kk = 0; kk < 8; kk++){
      bf16x8 hf[4];
      #pragma unroll
      for (int tt = 0; tt < 4; tt++){
        const int n = tt*16 + lr;
        hf[tt] = ldb8(&lt[n*256 + ((kk*32 + lg*8) ^ ((n&7)<<3))]);
      }
      #pragma unroll
      for (int ct = 0; ct < 4; ct++){
        bf16x8 wf = ldb8(wq + ((size_t)(co0 + ct*16 + lr) << 8) + kk*32 + lg*8);
        if (ch < 2){
          #pragma unroll
          for (int tt = 0; tt < 4; tt++)
            acc[ct][tt] = __builtin_amdgcn_mfma_f32_16x16x32_bf16(hf[tt], wf, acc[ct][tt], 0, 0, 0);
        } else {
          #pragma unroll
          for (int tt = 0; tt < 4; tt++)
            acc[ct][tt] = __builtin_amdgcn_mfma_f32_16x16x32_bf16(wf, hf[tt], acc[ct][tt], 0, 0, 0);
        }
      }
    }
    if (ch < 2){
      // D[n][co]: col = co0+ct*16+lr, rows n = tt*16+lg*4+i
      short* dst = (ch == 0) ? q_t : k_t;
      const int cb = co0 - ch*256;
      #pragma unroll
      for (int ct = 0; ct < 4; ct++){
        const float bias = bf2f(bq[co0 + ct*16 + lr]);
        #pragma unroll
        for (int tt = 0; tt < 4; tt++){
          #pragma unroll
          for (int i = 0; i < 4; i++){
            const int row = n0 + tt*16 + lg*4 + i;
            dst[(((size_t)b*4096 + row) << 8) + cb + ct*16 + lr] = f2bf(acc[ct][tt][i] + bias);
          }
        }
      }
    } else {
      // D[co][n]: rows co = co0+ct*16+lg*4+i, col n = tt*16+lr
      #pragma unroll
      for (int ct = 0; ct < 4; ct++){
        #pragma unroll
        for (int i = 0; i < 4; i++){
          const int co = co0 + ct*16 + lg*4 + i;
          const float bias = bf2f(bq[co]);
          #pragma unroll
          for (int tt = 0; tt < 4; tt++){
            v_buf[(((size_t)(b*256 + co - 512)) << 12) + n0 + tt*16 + lr] = f2bf(acc[ct][tt][i] + bias);
          }
        }
      }
    }
  }
}

// ======================= flash attention ===================================
// 4 waves x 32 q (QB=128), KB=32, 32x32x16 MFMA, swapped QK^T softmax,
// global_load_lds dbuf staging (round-4 proven schedule: 1 barrier/iter).
template<int NKH>
__global__ __launch_bounds__(256, 2) void attn_flash_t(
    const short* __restrict__ q_t, const short* __restrict__ k_t,
    const short* __restrict__ v_b, short* __restrict__ o0,
    short* __restrict__ o1, float* __restrict__ ml){
  constexpr int NT = 128 / NKH;
  const int b = blockIdx.x & 7;
  const int rest = blockIdx.x >> 3;
  const int kh = rest & (NKH - 1);
  const int qt = rest / NKH;
  const char* kbase = (const char*)(k_t + (((size_t)b*4096 + kh*NT*32) << 8));
  const char* vbase = (const char*)(v_b + (((size_t)b*256) << 12) + (size_t)kh*NT*32);

  const int t = threadIdx.x, w = t >> 6, l = t & 63;
  const int lq = l & 31, hi = l >> 5;
  const int q0 = qt*128 + w*32;

  __shared__ short smem[32768];   // 64 KB: [buf2][K 16KB | V 16KB]
  char* lds = (char*)smem;

  bf16x8 qf[16];
  {
    const short* pq = q_t + (((size_t)b*4096 + q0 + lq) << 8) + hi*8;
    #pragma unroll
    for (int ks = 0; ks < 16; ks++) qf[ks] = ldb8(pq + ks*16);
  }
  f32x16 of[8];
  #pragma unroll
  for (int ct = 0; ct < 8; ct++)
    #pragma unroll
    for (int r = 0; r < 16; r++) of[ct][r] = 0.f;
  float m_run = -1.0e30f, l_run = 0.f;

  const char* ksrc[4]; const char* vsrc[4];
  #pragma unroll
  for (int j = 0; j < 4; j++){
    const int key = w*8 + j*2 + hi;
    ksrc[j] = kbase + key*512 + (((l&31)*16) ^ ((key&15)<<4));
    const int c = w*64 + j*16 + (l>>2);
    vsrc[j] = vbase + (size_t)c*8192 + (((l&3)*16) ^ (((c>>1)&3)<<4));
  }

  #define STAGE(buf, kt_) do {                                               \
    _Pragma("unroll")                                                        \
    for (int j = 0; j < 4; j++)                                              \
      __builtin_amdgcn_global_load_lds(                                      \
        (const __attribute__((address_space(1))) unsigned*)(ksrc[j] + (size_t)(kt_)*16384), \
        (__attribute__((address_space(3))) unsigned*)(lds + (buf)*32768 + w*4096 + j*1024), \
        16, 0, 0);                                                           \
    _Pragma("unroll")                                                        \
    for (int j = 0; j < 4; j++)                                              \
      __builtin_amdgcn_global_load_lds(                                      \
        (const __attribute__((address_space(1))) unsigned*)(vsrc[j] + (size_t)(kt_)*64),    \
        (__attribute__((address_space(3))) unsigned*)(lds + (buf)*32768 + 16384 + w*4096 + j*1024), \
        16, 0, 0);                                                           \
  } while (0)

  STAGE(0, 0);
  __syncthreads();

  const int hi16 = hi*16;
  const int swzKr = (lq & 15) << 4;
  const int swzV  = ((lq >> 1) & 3) << 4;
  int cur = 0;

  for (int kt2 = 0; kt2 < NT; kt2++){
    if (kt2 + 1 < NT) STAGE(cur^1, kt2+1);
    const char* Kb = lds + cur*32768;
    const char* Vb = lds + cur*32768 + 16384;

    // ---- S^T = mfma(K, Q) ----
    f32x16 sf;
    #pragma unroll
    for (int r = 0; r < 16; r++) sf[r] = 0.f;
    #pragma unroll
    for (int ks = 0; ks < 16; ks++){
      bf16x8 kf = ldb8((const short*)(Kb + (lq<<9) + ((ks*32 + hi16) ^ swzKr)));
      sf = __builtin_amdgcn_mfma_f32_32x32x16_bf16(kf, qf[ks], sf, 0, 0, 0);
    }

    // ---- online softmax, in-register (lane pair l <-> l^32) ----
    float pm = sf[0];
    #pragma unroll
    for (int r = 1; r < 16; r++) pm = fmaxf(pm, sf[r]);
    pm = fmaxf(pm, __shfl_xor(pm, 32));
    if (!__all(pm <= m_run + 8.f)){          // defer-max (THR=8)
      const float mn = fmaxf(m_run, pm);
      const float corr = exp2f((m_run - mn) * LOG2E);
      #pragma unroll
      for (int ct = 0; ct < 8; ct++)
        #pragma unroll
        for (int r = 0; r < 16; r++) of[ct][r] *= corr;
      l_run *= corr;
      m_run = mn;
    }
    const float mL = m_run * LOG2E;
    float p[16]; float s = 0.f;
    #pragma unroll
    for (int r = 0; r < 16; r++){
      p[r] = exp2f(__builtin_fmaf(sf[r], LOG2E, -mL));
      s += p[r];
    }
    l_run += s + __shfl_xor(s, 32);

    // ---- pack P -> bf16 A-frags (native cvt_pk; exchange with lane^32) ----
    unsigned own[8];
    #pragma unroll
    for (int ks = 0; ks < 2; ks++){
      own[ks*4+0] = pk2(p[ks*8+0], p[ks*8+1]);
      own[ks*4+1] = pk2(p[ks*8+2], p[ks*8+3]);
      own[ks*4+2] = pk2(p[ks*8+4], p[ks*8+5]);
      own[ks*4+3] = pk2(p[ks*8+6], p[ks*8+7]);
    }
    unsigned prt[8];
    #pragma unroll
    for (int i = 0; i < 8; i++) prt[i] = __shfl_xor(own[i], 32);
    bf16x8 pfrag[2];
    #pragma unroll
    for (int ks = 0; ks < 2; ks++){
      union { unsigned u[4]; bf16x8 v; } uu;
      uu.u[0] = hi ? prt[ks*4+2] : own[ks*4+0];
      uu.u[1] = hi ? prt[ks*4+3] : own[ks*4+1];
      uu.u[2] = hi ? own[ks*4+2] : prt[ks*4+0];
      uu.u[3] = hi ? own[ks*4+3] : prt[ks*4+1];
      pfrag[ks] = uu.v;
    }

    // ---- PV ----
    #pragma unroll
    for (int ks = 0; ks < 2; ks++){
      #pragma unroll
      for (int ct = 0; ct < 8; ct++){
        bf16x8 vf = ldb8((const short*)(Vb + ((ct*32 + lq)<<6) + ((ks*32 + hi16) ^ swzV)));
        of[ct] = __builtin_amdgcn_mfma_f32_32x32x16_bf16(pfrag[ks], vf, of[ct], 0, 0, 0);
      }
    }
    __syncthreads();
    cur ^= 1;
  }
  #undef STAGE

  short* ohp;
  if constexpr (NKH == 1) ohp = o0; else ohp = kh ? o1 : o0;
  short* po = ohp + (((size_t)b*4096 + q0) << 8);
  #pragma unroll
  for (int r = 0; r < 16; r++){
    const int row = (r&3) + 8*(r>>2) + 4*hi;
    const float lv = __shfl(l_run, row);
    const float inv = __builtin_amdgcn_rcpf(lv);
    #pragma unroll
    for (int ct = 0; ct < 8; ct++){
      po[(size_t)row*256 + ct*32 + lq] = f2bf(of[ct][r] * inv);
    }
  }
  if constexpr (NKH > 1){
    if (l < 32){
      const size_t mi = (((size_t)(kh*8 + b))*4096 + q0 + l)*2;
      ml[mi]   = m_run;
      ml[mi+1] = l_run;
    }
  }
}

// ---------------- K5: proj GEMM + bias + residual (+ fused split-merge) ----
template<int MERGE>
__global__ __launch_bounds__(256) void proj_res(
    const short* __restrict__ o0, const short* __restrict__ o1,
    const float* __restrict__ ml, const short* __restrict__ wp,
    const float* __restrict__ bp, const float* __restrict__ x,
    float* __restrict__ out){
  const int b = blockIdx.x >> 6, qt = blockIdx.x & 63;
  const int q0 = qt << 6;
  const int t = threadIdx.x, w = t >> 6, lane = t & 63;
  const int lr = lane & 15, lg = lane >> 4;

  float a0[4], a1[4];
  if constexpr (MERGE){
    #pragma unroll
    for (int tt = 0; tt < 4; tt++){
      const int q = q0 + tt*16 + lr;
      const size_t m0i = (((size_t)b)*4096 + q)*2;
      const size_t m1i = (((size_t)(8 + b))*4096 + q)*2;
      const float m0 = ml[m0i], l0 = ml[m0i+1];
      const float m1 = ml[m1i], l1 = ml[m1i+1];
      const float M  = fmaxf(m0, m1);
      const float w0 = l0 * exp2f((m0 - M) * LOG2E);
      const float w1 = l1 * exp2f((m1 - M) * LOG2E);
      const float inv = 1.f / (w0 + w1);
      a0[tt] = w0 * inv; a1[tt] = w1 * inv;
    }
  }

  f32x4 acc[4][4];
  #pragma unroll
  for (int cg = 0; cg < 4; cg++)
    #pragma unroll
    for (int tt = 0; tt < 4; tt++) acc[cg][tt] = (f32x4){0.f,0.f,0.f,0.f};

  #pragma unroll
  for (int kk = 0; kk < 8; kk++){
    bf16x8 bfr[4];
    #pragma unroll
    for (int tt = 0; tt < 4; tt++){
      const size_t off = (((size_t)b*4096 + q0 + tt*16 + lr) << 8) + kk*32 + lg*8;
      if constexpr (MERGE){
        s16x8 v0 = *(const s16x8*)(o0 + off);
        s16x8 v1 = *(const s16x8*)(o1 + off);
        union { __bf16 h[8]; bf16x8 v; } r;
        #pragma unroll
        for (int e = 0; e < 8; e++)
          r.h[e] = (__bf16)(a0[tt]*bf2f(v0[e]) + a1[tt]*bf2f(v1[e]));
        bfr[tt] = r.v;
      } else {
        bfr[tt] = ldb8(o0 + off);
      }
    }
    #pragma unroll
    for (int cg = 0; cg < 4; cg++){
      bf16x8 af = ldb8(wp + (((size_t)(cg*64 + w*16 + lr)) << 8) + kk*32 + lg*8);
      #pragma unroll
      for (int tt = 0; tt < 4; tt++)
        acc[cg][tt] = __builtin_amdgcn_mfma_f32_16x16x32_bf16(af, bfr[tt], acc[cg][tt], 0, 0, 0);
    }
  }
  #pragma unroll
  for (int cg = 0; cg < 4; cg++){
    #pragma unroll
    for (int i = 0; i < 4; i++){
      const int co = cg*64 + w*16 + lg*4 + i;
      const float bias = bp[co];
      #pragma unroll
      for (int tt = 0; tt < 4; tt++){
        const int q = q0 + tt*16 + lr;
        const size_t idx = (((size_t)(b*256 + co)) << 12) + q;
        out[idx] = acc[cg][tt][i] + bias + x[idx];
      }
    }
  }
}

// ---------------- workspace layout -----------------------------------------
static constexpr size_t SZT  = (size_t)8 * 4096 * 256 * 2;  // 16 MB bf16 tensor
static constexpr size_t OFF_STATS = 0;                      // 2 KB
static constexpr size_t OFF_WQ = 4096;
static constexpr size_t OFF_BQ = OFF_WQ + 768*256*2;
static constexpr size_t OFF_WP = OFF_BQ + 768*2;
static constexpr size_t OFF_BP = OFF_WP + 256*256*2;
static constexpr size_t OFF_HT = 532480;                    // oh0
static constexpr size_t OFF_QT = OFF_HT + SZT;
static constexpr size_t OFF_KT = OFF_QT + SZT;
static constexpr size_t OFF_V  = OFF_KT + SZT;
static constexpr size_t OFF_OT = OFF_V + SZT;
static constexpr size_t OFF_OH1 = OFF_OT + SZT;
static constexpr size_t OFF_ML  = OFF_OH1 + SZT;
static constexpr size_t WS_NEED_SPLIT = OFF_ML + (size_t)2*8*4096*2*4;

extern "C" void kernel_launch(void* const* d_in, const int* in_sizes, int n_in,
                              void* d_out, int out_size, void* d_ws, size_t ws_size,
                              hipStream_t stream){
  const float* x    = (const float*)d_in[0];
  const float* nw   = (const float*)d_in[1];
  const float* nb   = (const float*)d_in[2];
  const float* qkvw = (const float*)d_in[3];
  const float* qkvb = (const float*)d_in[4];
  const float* pw   = (const float*)d_in[5];
  const float* pb   = (const float*)d_in[6];
  float* out = (float*)d_out;
  char* ws = (char*)d_ws;

  float* stats = (float*)(ws + OFF_STATS);
  short* wq    = (short*)(ws + OFF_WQ);
  short* bq    = (short*)(ws + OFF_BQ);
  short* wp    = (short*)(ws + OFF_WP);
  float* bp    = (float*)(ws + OFF_BP);
  short* oh0   = (short*)(ws + OFF_HT);
  short* qt    = (short*)(ws + OFF_QT);
  short* kt    = (short*)(ws + OFF_KT);
  short* vb    = (short*)(ws + OFF_V);
  short* ot    = (short*)(ws + OFF_OT);
  short* oh1   = (short*)(ws + OFF_OH1);
  float* ml    = (float*)(ws + OFF_ML);

  prep_w  <<<256, 256, 0, stream>>>(qkvw, qkvb, pw, pb, wq, bq, wp, bp);
  gn_stats<<<256, 256, 0, stream>>>(x, stats);
  gn_qkv  <<<512, 256, 0, stream>>>(x, stats, nw, nb, wq, bq, qt, kt, vb);
  if (ws_size >= WS_NEED_SPLIT){
    attn_flash_t<2><<<512, 256, 0, stream>>>(qt, kt, vb, oh0, oh1, ml);
    proj_res<1>    <<<512, 256, 0, stream>>>(oh0, oh1, ml, wp, bp, x, out);
  } else {
    attn_flash_t<1><<<256, 256, 0, stream>>>(qt, kt, vb, ot, ot, ml);
    proj_res<0>    <<<512, 256, 0, stream>>>(ot, ot, ml, wp, bp, x, out);
  }
}